// Round 8
// baseline (3037.195 us; speedup 1.0000x reference)
//
#include <hip/hip_runtime.h>
#include <hip/hip_bf16.h>

#define D_MODEL 128
#define INNER 256
#define NH 4
#define DHM 64
#define SNH 4
#define SDH 32
#define FF 192
#define CK 4
#define BATCH 64
#define SEQ 256
#define T_TOK (BATCH*SEQ)   /* 16384 tokens */

typedef __hip_bfloat16 bf16;

__device__ __forceinline__ float sigf(float x){ return 1.0f/(1.0f+__expf(-x)); }
__device__ __forceinline__ float bcast_lane(float v, int k){
    return __uint_as_float(__builtin_amdgcn_readlane(__float_as_uint(v), k));
}
__device__ __forceinline__ float frcp(float x){ return __builtin_amdgcn_rcpf(x); }

// ---------------- sentinel writer (fp32) ----------------
__global__ void sentinel_kernel(float* __restrict__ out, float v)
{
    int idx = threadIdx.x;
    if (idx < BATCH*3) out[idx] = v;
}

// ---------------- embed ----------------
__global__ void embed_kernel(const float* __restrict__ x, const float* __restrict__ W,
                             const float* __restrict__ bias, float* __restrict__ h)
{
    int idx = blockIdx.x*blockDim.x + threadIdx.x;   // T*128
    if (idx >= T_TOK*D_MODEL) return;
    int d = idx & 127; int t = idx >> 7;
    float s = bias[d];
    #pragma unroll
    for (int i = 0; i < 3; ++i) s += x[t*3+i] * W[i*D_MODEL+d];
    h[idx] = s;
}

// ---------------- LN: one WAVE (64 threads) per token, coalesced ----------------
__global__ void ln_kernel(const float* __restrict__ x, const float* __restrict__ w,
                          float* __restrict__ out)
{
    int t = blockIdx.x; int lane = threadIdx.x;      // 64 threads
    float v0 = x[(size_t)t*128 + lane], v1 = x[(size_t)t*128 + 64 + lane];
    float s = v0 + v1, ss = v0*v0 + v1*v1;
    #pragma unroll
    for (int off = 32; off >= 1; off >>= 1){ s += __shfl_xor(s,off); ss += __shfl_xor(ss,off); }
    float mu  = s * (1.f/128.f);
    float var = fmaxf(ss * (1.f/128.f) - mu*mu, 0.f);
    float r   = rsqrtf(var + 1e-6f);
    out[(size_t)t*128 + lane]      = (v0-mu)*r*w[lane];
    out[(size_t)t*128 + 64 + lane] = (v1-mu)*r*w[64+lane];
}

// ---------------- tiled GEMM 64x64: C[M,N] (+)= A[M,K] * W[K,N] ----------------
#define TM 64
#define TN 64
#define TK 32
__global__ void __launch_bounds__(256)
gemm_tiled_kernel(const float* __restrict__ A, const float* __restrict__ W,
                  float* __restrict__ C, int M, int N, int Kd, int acc)
{
    int ntiles = N / TN;
    int bx = blockIdx.x % ntiles;
    int by = blockIdx.x / ntiles;
    __shared__ float As[TK][TM+1];   // +1 pad: kills 32-way write conflicts
    __shared__ float Ws[TK][TN];
    int tid = threadIdx.x;
    int tn = (tid & 15) * 4;         // col within tile
    int tm = (tid >> 4) * 4;         // row within tile
    float accr[4][4] = {{0.f}};
    for (int k0 = 0; k0 < Kd; k0 += TK){
        #pragma unroll
        for (int i = tid; i < TM*TK; i += 256){
            int c2 = i & 31, r = i >> 5;             // k fastest -> coalesced global
            As[c2][r] = A[(size_t)(by*TM + r)*Kd + k0 + c2];
        }
        #pragma unroll
        for (int i = tid; i < TK*TN; i += 256){
            int c2 = i & 63, r = i >> 6;             // n fastest -> coalesced global
            Ws[r][c2] = W[(size_t)(k0 + r)*N + bx*TN + c2];
        }
        __syncthreads();
        #pragma unroll
        for (int k = 0; k < TK; ++k){
            float a0 = As[k][tm], a1 = As[k][tm+1], a2 = As[k][tm+2], a3 = As[k][tm+3];
            float4 wv = *(const float4*)&Ws[k][tn];
            accr[0][0] = fmaf(a0, wv.x, accr[0][0]); accr[0][1] = fmaf(a0, wv.y, accr[0][1]);
            accr[0][2] = fmaf(a0, wv.z, accr[0][2]); accr[0][3] = fmaf(a0, wv.w, accr[0][3]);
            accr[1][0] = fmaf(a1, wv.x, accr[1][0]); accr[1][1] = fmaf(a1, wv.y, accr[1][1]);
            accr[1][2] = fmaf(a1, wv.z, accr[1][2]); accr[1][3] = fmaf(a1, wv.w, accr[1][3]);
            accr[2][0] = fmaf(a2, wv.x, accr[2][0]); accr[2][1] = fmaf(a2, wv.y, accr[2][1]);
            accr[2][2] = fmaf(a2, wv.z, accr[2][2]); accr[2][3] = fmaf(a2, wv.w, accr[2][3]);
            accr[3][0] = fmaf(a3, wv.x, accr[3][0]); accr[3][1] = fmaf(a3, wv.y, accr[3][1]);
            accr[3][2] = fmaf(a3, wv.z, accr[3][2]); accr[3][3] = fmaf(a3, wv.w, accr[3][3]);
        }
        __syncthreads();
    }
    #pragma unroll
    for (int i = 0; i < 4; ++i){
        size_t off = (size_t)(by*TM + tm + i)*N + bx*TN + tn;
        if (acc){
            float4 old = *(float4*)&C[off];
            old.x += accr[i][0]; old.y += accr[i][1];
            old.z += accr[i][2]; old.w += accr[i][3];
            *(float4*)&C[off] = old;
        } else {
            *(float4*)&C[off] = make_float4(accr[i][0], accr[i][1], accr[i][2], accr[i][3]);
        }
    }
}

// ---------------- causal conv (K=4) + silu ----------------
__global__ void conv_silu_kernel(const float* __restrict__ in, int istride,
                                 const float* __restrict__ w, const float* __restrict__ bias,
                                 float* __restrict__ out, int C)
{
    int idx = blockIdx.x*blockDim.x + threadIdx.x;   // T*C
    if (idx >= T_TOK*C) return;
    int c = idx % C; int t = idx / C;
    int s = t & (SEQ-1); int b = t >> 8;
    float a = bias[c];
    int j0 = (s >= CK-1) ? s-(CK-1) : 0;
    for (int j = j0; j <= s; ++j){
        int k = j - s + (CK-1);
        a += in[(size_t)(b*SEQ+j)*istride + c] * w[c*CK + k];
    }
    out[idx] = a * sigf(a);
}

// ---------------- headwise 4x4 projection ----------------
__global__ void headwise_kernel(const float* __restrict__ in, int istride,
                                const float* __restrict__ W, float* __restrict__ out)
{
    int idx = blockIdx.x*blockDim.x + threadIdx.x;   // T*256
    if (idx >= T_TOK*INNER) return;
    int c = idx & 255; int t = idx >> 8;
    int n = c >> 2, l = c & 3;
    const float* xr = in + (size_t)t*istride + n*4;
    float s = 0.f;
    for (int k = 0; k < 4; ++k) s += xr[k] * W[n*16 + k*4 + l];
    out[idx] = s;
}

__global__ void headwise_inplace_kernel(float* __restrict__ up, const float* __restrict__ W)
{
    int idx = blockIdx.x*blockDim.x + threadIdx.x;   // T*64
    if (idx >= T_TOK*64) return;
    int n = idx & 63; int t = idx >> 6;
    float* xr = up + (size_t)t*512 + n*4;
    float x0 = xr[0], x1 = xr[1], x2 = xr[2], x3 = xr[3];
    const float* w = W + n*16;
    for (int l = 0; l < 4; ++l)
        xr[l] = x0*w[l] + x1*w[4+l] + x2*w[8+l] + x3*w[12+l];
}

// ---------------- ig/fg projection: one WAVE per token ---------------------------
__global__ void __launch_bounds__(256)
gateproj_kernel(const float* __restrict__ q, const float* __restrict__ k,
                const float* __restrict__ up,
                const float* __restrict__ Wig, const float* __restrict__ big,
                const float* __restrict__ Wfg, const float* __restrict__ bfg,
                float* __restrict__ igt, float* __restrict__ fgt)
{
    int t = blockIdx.x*4 + (threadIdx.x >> 6);       // token; 4 waves/block
    int lane = threadIdx.x & 63;
    float4 si = make_float4(0.f,0.f,0.f,0.f);
    float4 sf = make_float4(0.f,0.f,0.f,0.f);
    #pragma unroll
    for (int c = 0; c < 12; ++c){
        int j = c*64 + lane;
        float xv;
        if (c < 4)      xv = q[(size_t)t*256 + j];
        else if (c < 8) xv = k[(size_t)t*256 + j - 256];
        else            xv = up[(size_t)t*512 + j - 512];   // v in up[:, :256]
        float4 wi = *(const float4*)(Wig + (size_t)j*4);
        float4 wf = *(const float4*)(Wfg + (size_t)j*4);
        si.x = fmaf(xv, wi.x, si.x); si.y = fmaf(xv, wi.y, si.y);
        si.z = fmaf(xv, wi.z, si.z); si.w = fmaf(xv, wi.w, si.w);
        sf.x = fmaf(xv, wf.x, sf.x); sf.y = fmaf(xv, wf.y, sf.y);
        sf.z = fmaf(xv, wf.z, sf.z); sf.w = fmaf(xv, wf.w, sf.w);
    }
    #pragma unroll
    for (int off = 32; off >= 1; off >>= 1){
        si.x += __shfl_xor(si.x, off); si.y += __shfl_xor(si.y, off);
        si.z += __shfl_xor(si.z, off); si.w += __shfl_xor(si.w, off);
        sf.x += __shfl_xor(sf.x, off); sf.y += __shfl_xor(sf.y, off);
        sf.z += __shfl_xor(sf.z, off); sf.w += __shfl_xor(sf.w, off);
    }
    int b = t >> 8, s = t & 255;
    int hh = lane & 3;
    float vi = (hh==0) ? si.x : (hh==1) ? si.y : (hh==2) ? si.z : si.w;
    float vf = (hh==0) ? sf.x : (hh==1) ? sf.y : (hh==2) ? sf.z : sf.w;
    if (lane < 4)       igt[(b*4+hh)*SEQ + s] = vi + big[hh];
    else if (lane < 8)  fgt[(b*4+hh)*SEQ + s] = vf + bfg[hh];
}

// ---------------- cs: one WAVE per (b,h), parallel logsigmoid + wave scan --------
__global__ void __launch_bounds__(64)
cs_kernel(const float* __restrict__ fgt, const float* __restrict__ igt,
          float* __restrict__ cs, float* __restrict__ pm)
{
    int bh = blockIdx.x;                             // 256 blocks
    int lane = threadIdx.x;                          // 64
    float4 f4 = *(const float4*)(fgt + (size_t)bh*SEQ + lane*4);
    float4 i4 = *(const float4*)(igt + (size_t)bh*SEQ + lane*4);
    float lf0, lf1, lf2, lf3;
    { float f = f4.x; lf0 = (f > 0.f) ? -log1pf(__expf(-f)) : f - log1pf(__expf(f)); }
    { float f = f4.y; lf1 = (f > 0.f) ? -log1pf(__expf(-f)) : f - log1pf(__expf(f)); }
    { float f = f4.z; lf2 = (f > 0.f) ? -log1pf(__expf(-f)) : f - log1pf(__expf(f)); }
    { float f = f4.w; lf3 = (f > 0.f) ? -log1pf(__expf(-f)) : f - log1pf(__expf(f)); }
    float p0 = lf0, p1 = p0 + lf1, p2 = p1 + lf2, p3 = p2 + lf3;
    float incl = p3;
    #pragma unroll
    for (int off = 1; off < 64; off <<= 1){
        float v = __shfl_up(incl, off);
        if (lane >= off) incl += v;
    }
    float excl = __shfl_up(incl, 1);
    if (lane == 0) excl = 0.f;
    float c0 = excl + p0, c1 = excl + p1, c2 = excl + p2, c3 = excl + p3;
    *(float4*)(cs + (size_t)bh*SEQ + lane*4) = make_float4(c0, c1, c2, c3);
    float u0 = i4.x - c0, u1 = i4.y - c1, u2 = i4.z - c2, u3 = i4.w - c3;
    float m0 = u0, m1 = fmaxf(m0, u1), m2 = fmaxf(m1, u2), m3 = fmaxf(m2, u3);
    float inm = m3;
    #pragma unroll
    for (int off = 1; off < 64; off <<= 1){
        float v = __shfl_up(inm, off);
        if (lane >= off) inm = fmaxf(inm, v);
    }
    float exm = __shfl_up(inm, 1);
    if (lane == 0) exm = -1e30f;
    *(float4*)(pm + (size_t)bh*SEQ + lane*4) =
        make_float4(fmaxf(exm, m0), fmaxf(exm, m1), fmaxf(exm, m2), fmaxf(exm, m3));
}

// ---------------- attention v7: 2 Q-rows per lane (LDS-issue halving) ------------
// Round-7 counters: LDS-issue-bound (~3.4K LDS cyc vs ~2K VALU cyc per chunk-wave).
// Every K/V/S LDS read is per-WAVE; feeding 2 rows per lane doubles FMA per read
// -> VALU-bound. Block = (b,h,qt of 128 rows), rows il and il+64 per thread.
// doA (wave-uniform) skips lower-row work in fully-masked chunks. Grid 512,
// qt = blk>>8 so each CU mixes short/long blocks. No launch-bounds min (r5 lesson).
#define AC 32
__global__ void __launch_bounds__(256)
attn_kernel(float* __restrict__ q, const float* __restrict__ kk,
            const float* __restrict__ up,
            const float* __restrict__ igt, const float* __restrict__ cs,
            const float* __restrict__ pm)
{
    __shared__ float k_sh[AC][DHM];      // 8 KB
    __shared__ float v_sh[AC][DHM];      // 8 KB
    __shared__ float S_sh[128][33];      // 16.9 KB
    __shared__ float u_sh[SEQ];          // 1 KB
    int blk = blockIdx.x;
    int qt = blk >> 8, bh = blk & 255;
    int b = bh >> 2, hh = bh & 3;
    int tid = threadIdx.x;
    int il = tid & 63;                   // local row (upper half: il+64)
    int g = tid >> 6;                    // 0..3: phase1 j-eighth; phase2 d-quarter
    int iA = qt*128 + il;
    int iB = iA + 64;
    u_sh[tid] = igt[bh*SEQ + tid] - cs[bh*SEQ + tid];
    float csiA = cs[bh*SEQ + iA], mA = csiA + pm[bh*SEQ + iA];
    float csiB = cs[bh*SEQ + iB], mB = csiB + pm[bh*SEQ + iB];
    const float4* qpA = (const float4*)(q + ((size_t)(b*SEQ + iA)*INNER + hh*DHM));
    const float4* qpB = (const float4*)(q + ((size_t)(b*SEQ + iB)*INNER + hh*DHM));
    float4 qA[16], qB[16];
    #pragma unroll
    for (int r = 0; r < 16; ++r){ qA[r] = qpA[r]; qB[r] = qpB[r]; }
    float4 accA[4], accB[4];
    #pragma unroll
    for (int r = 0; r < 4; ++r){
        accA[r] = make_float4(0.f,0.f,0.f,0.f);
        accB[r] = make_float4(0.f,0.f,0.f,0.f);
    }
    float ssA = 0.f, ssB = 0.f;
    int cend = (qt+1)*128;

    for (int c0 = 0; c0 < cend; c0 += AC){
        // stage K/V chunk: 256 threads cover 2*32*16 float4 (4 each)
        {
            int half = tid >> 7;         // 0: K  1: V
            int idx2 = tid & 127;
            int r0 = idx2 >> 4;          // 0..7
            int d4 = idx2 & 15;
            #pragma unroll
            for (int rr = 0; rr < 4; ++rr){
                int r = r0 + rr*8;
                size_t tj = (size_t)(b*SEQ + c0 + r);
                if (half == 0)
                    ((float4*)&k_sh[r][0])[d4] = *(const float4*)(kk + tj*INNER + hh*DHM + d4*4);
                else
                    ((float4*)&v_sh[r][0])[d4] = *(const float4*)(up + tj*512 + hh*DHM + d4*4);
            }
        }
        __syncthreads();
        bool doA = (c0 < qt*128 + 64);   // wave-uniform: lower rows not fully masked
        // phase1: 8 dots for row B (always) and row A (if doA), sharing K reads
        #pragma unroll
        for (int jj = 0; jj < 8; ++jj){
            int jl = g*8 + jj;
            const float4* kr = (const float4*)&k_sh[jl][0];
            float a0=0.f, a1=0.f, a2=0.f, a3=0.f;
            float b0=0.f, b1=0.f, b2=0.f, b3=0.f;
            #pragma unroll
            for (int r4 = 0; r4 < 4; ++r4){
                float4 ka = kr[r4*4+0], kb2 = kr[r4*4+1];
                float4 kc = kr[r4*4+2], kd  = kr[r4*4+3];
                float4 qa = qB[r4*4+0], qb2 = qB[r4*4+1];
                float4 qc = qB[r4*4+2], qd  = qB[r4*4+3];
                b0 += qa.x*ka.x + qa.y*ka.y + qa.z*ka.z + qa.w*ka.w;
                b1 += qb2.x*kb2.x + qb2.y*kb2.y + qb2.z*kb2.z + qb2.w*kb2.w;
                b2 += qc.x*kc.x + qc.y*kc.y + qc.z*kc.z + qc.w*kc.w;
                b3 += qd.x*kd.x + qd.y*kd.y + qd.z*kd.z + qd.w*kd.w;
                if (doA){
                    float4 pa = qA[r4*4+0], pb2 = qA[r4*4+1];
                    float4 pc = qA[r4*4+2], pd  = qA[r4*4+3];
                    a0 += pa.x*ka.x + pa.y*ka.y + pa.z*ka.z + pa.w*ka.w;
                    a1 += pb2.x*kb2.x + pb2.y*kb2.y + pb2.z*kb2.z + pb2.w*kb2.w;
                    a2 += pc.x*kc.x + pc.y*kc.y + pc.z*kc.z + pc.w*kc.w;
                    a3 += pd.x*kd.x + pd.y*kd.y + pd.z*kd.z + pd.w*kd.w;
                }
            }
            int jg = c0 + jl;
            float dotB = (b0+b1) + (b2+b3);
            float argB = fminf(csiB + u_sh[jg] - mB, 0.f);
            S_sh[il+64][jl] = (jg <= iB) ? dotB * 0.125f * __expf(argB) : 0.f;
            if (doA){
                float dotA = (a0+a1) + (a2+a3);
                float argA = fminf(csiA + u_sh[jg] - mA, 0.f);
                S_sh[il][jl] = (jg <= iA) ? dotA * 0.125f * __expf(argA) : 0.f;
            }
        }
        __syncthreads();
        // phase2: 16 output dims for both rows over the chunk's 32 j's, sharing V
        #pragma unroll
        for (int jj = 0; jj < AC; ++jj){
            float svB = S_sh[il+64][jj];
            float svA = doA ? S_sh[il][jj] : 0.f;   // stale S selected to 0 when !doA
            ssB += svB; ssA += svA;
            const float4* vr = (const float4*)&v_sh[jj][g*16];
            #pragma unroll
            for (int r = 0; r < 4; ++r){
                float4 vv = vr[r];
                accB[r].x += svB*vv.x; accB[r].y += svB*vv.y;
                accB[r].z += svB*vv.z; accB[r].w += svB*vv.w;
                accA[r].x += svA*vv.x; accA[r].y += svA*vv.y;
                accA[r].z += svA*vv.z; accA[r].w += svA*vv.w;
            }
        }
        __syncthreads();
    }
    float rnA = 1.f/(fmaxf(fabsf(ssA), __expf(-mA)) + 1e-6f);
    float rnB = 1.f/(fmaxf(fabsf(ssB), __expf(-mB)) + 1e-6f);
    float4* opA = (float4*)(q + ((size_t)(b*SEQ + iA)*INNER + hh*DHM + g*16));
    float4* opB = (float4*)(q + ((size_t)(b*SEQ + iB)*INNER + hh*DHM + g*16));
    #pragma unroll
    for (int r = 0; r < 4; ++r){
        float4 oA = accA[r];
        oA.x *= rnA; oA.y *= rnA; oA.z *= rnA; oA.w *= rnA;
        opA[r] = oA;
        float4 oB = accB[r];
        oB.x *= rnB; oB.y *= rnB; oB.z *= rnB; oB.w *= rnB;
        opB[r] = oB;
    }
}

__global__ void mh_gate_kernel(float* __restrict__ q, const float* __restrict__ up,
                               const float* __restrict__ xc,
                               const float* __restrict__ gnw, const float* __restrict__ skip)
{
    int idx = blockIdx.x*blockDim.x + threadIdx.x;   // T*4
    if (idx >= T_TOK*NH) return;
    int hh = idx & 3; int t = idx >> 2;
    float* qp = q + (size_t)t*256 + hh*DHM;
    float s = 0.f;
    for (int d = 0; d < DHM; ++d) s += qp[d];
    float mu = s * (1.f/64.f);
    float v = 0.f;
    for (int d = 0; d < DHM; ++d){ float dv = qp[d]-mu; v += dv*dv; }
    float r = rsqrtf(v * (1.f/64.f) + 1e-6f);
    for (int d = 0; d < DHM; ++d){
        int c = hh*DHM + d;
        float hn = (qp[d]-mu)*r*gnw[c];
        float z  = up[(size_t)t*512 + 256 + c];
        qp[d] = (hn + skip[c]*xc[(size_t)t*256 + c]) * (z*sigf(z));
    }
}

// ---------------- sLSTM gates: weight-stationary registers -----------------------
#define SG_TOK 16
__global__ void __launch_bounds__(512)
slstm_gates_kernel(const float* __restrict__ xc, const float* __restrict__ xl,
                   const float* __restrict__ Wg, const float* __restrict__ bg,
                   float* __restrict__ gates)
{
    int tid = threadIdx.x;
    int l  = tid & 31;
    int gn = tid >> 5;            // g*4+n
    int g  = gn >> 2, n = gn & 3;
    int t0 = blockIdx.x * SG_TOK;
    float wr[32];
    #pragma unroll
    for (int k = 0; k < 32; ++k) wr[k] = Wg[(size_t)gn*1024 + k*32 + l];
    float bias = bg[g*128 + n*32 + l];
    const float* xin = (g < 2) ? xc : xl;
    #pragma unroll 4
    for (int t = 0; t < SG_TOK; ++t){
        int tok = t0 + t;
        const float4* xr = (const float4*)(xin + (size_t)tok*128 + n*32);
        float a = bias;
        #pragma unroll
        for (int k4 = 0; k4 < 8; ++k4){
            float4 xv = xr[k4];
            a = fmaf(xv.x, wr[k4*4+0], a);
            a = fmaf(xv.y, wr[k4*4+1], a);
            a = fmaf(xv.z, wr[k4*4+2], a);
            a = fmaf(xv.w, wr[k4*4+3], a);
        }
        int b = tok >> 8, s = tok & 255;
        gates[(size_t)((b*4+n)*SEQ + s)*128 + l*4 + g] = a;
    }
}

// ---------------- sLSTM recurrence: shortened critical path ----------------------
__global__ void __launch_bounds__(64)
slstm_scan_kernel(const float* __restrict__ gates, const float* __restrict__ Rw,
                  float* __restrict__ ys)
{
    int bn = blockIdx.x;                 // b*4 + n
    int b = bn >> 2, n = bn & 3;
    int lane = threadIdx.x;              // 0..63
    int l = lane & 31;
    int hi = lane >> 5;                  // 0: gates i,f   1: gates z,o
    int gA = hi ? 2 : 0, gB = hi ? 3 : 1;
    const float* Rbase = Rw + (size_t)n*1024 + l;
    float Ra[32], Rb[32];
    #pragma unroll
    for (int k = 0; k < 32; ++k){
        Ra[k] = Rbase[(size_t)gA*4096 + k*32];
        Rb[k] = Rbase[(size_t)gB*4096 + k*32];
    }
    const float* gbase = gates + (size_t)bn*SEQ*128 + l*4 + (hi ? 2 : 0);
    float* yrow = ys + (size_t)b*SEQ*128 + n*32 + l;
    float2 g0 = *(const float2*)(gbase);
    float2 g1 = *(const float2*)(gbase + 128);
    float c = 0.f, nst = 0.f, m = 0.f, hst = 0.f;
    for (int s = 0; s < SEQ; ++s){
        float2 g2 = (s+2 < SEQ) ? *(const float2*)(gbase + (size_t)(s+2)*128)
                                : make_float2(0.f, 0.f);
        float ra0=0.f, ra1=0.f, ra2=0.f, ra3=0.f;
        float rb0=0.f, rb1=0.f, rb2=0.f, rb3=0.f;
        #pragma unroll
        for (int k = 0; k < 8; ++k){
            float h0 = bcast_lane(hst, k);
            float h1 = bcast_lane(hst, k+8);
            float h2 = bcast_lane(hst, k+16);
            float h3 = bcast_lane(hst, k+24);
            ra0 = fmaf(h0, Ra[k],    ra0); rb0 = fmaf(h0, Rb[k],    rb0);
            ra1 = fmaf(h1, Ra[k+8],  ra1); rb1 = fmaf(h1, Rb[k+8],  rb1);
            ra2 = fmaf(h2, Ra[k+16], ra2); rb2 = fmaf(h2, Rb[k+16], rb2);
            ra3 = fmaf(h3, Ra[k+24], ra3); rb3 = fmaf(h3, Rb[k+24], rb3);
        }
        float ra = (ra0+ra1) + (ra2+ra3);
        float rb = (rb0+rb1) + (rb2+rb3);
        float pa = g0.x + ra;            // lo: ir   hi: zr
        float pb = g0.y + rb;            // lo: fr   hi: orr
        float zr  = __shfl_xor(pa, 32);
        float orr = __shfl_xor(pb, 32);
        float mnew = fmaxf(pb + m, pa);
        float iv = __expf(pa - mnew);
        float fv = __expf(pb + m - mnew);
        float zt = 1.f - 2.f*frcp(1.f + __expf(2.f*zr));
        float ov = frcp(1.f + __expf(-orr));
        c   = fv*c + iv*zt;
        nst = fv*nst + iv;
        hst = ov * c * frcp(nst + 1e-8f);
        m = mnew;
        if (!hi) yrow[(size_t)s*128] = hst;
        g0 = g1; g1 = g2;
    }
}

__global__ void mh_add_kernel(const float* __restrict__ ys, const float* __restrict__ gnw,
                              float* __restrict__ h)
{
    int idx = blockIdx.x*blockDim.x + threadIdx.x;   // T*4
    if (idx >= T_TOK*SNH) return;
    int n = idx & 3; int t = idx >> 2;
    const float* yr = ys + (size_t)t*128 + n*32;
    float s = 0.f;
    for (int l = 0; l < 32; ++l) s += yr[l];
    float mu = s * (1.f/32.f);
    float v = 0.f;
    for (int l = 0; l < 32; ++l){ float dv = yr[l]-mu; v += dv*dv; }
    float r = rsqrtf(v * (1.f/32.f) + 1e-6f);
    for (int l = 0; l < 32; ++l)
        h[(size_t)t*128 + n*32 + l] += (yr[l]-mu)*r*gnw[n*32+l];
}

__global__ void geluv_kernel(const float* __restrict__ up, float* __restrict__ out)
{
    int idx = blockIdx.x*blockDim.x + threadIdx.x;   // T*192
    if (idx >= T_TOK*FF) return;
    int j = idx % FF; int t = idx / FF;
    float g  = up[(size_t)t*384 + j];
    float vv = up[(size_t)t*384 + FF + j];
    float gel = 0.5f*g*(1.f + tanhf(0.7978845608028654f*(g + 0.044715f*g*g*g)));
    out[idx] = gel*vv;
}

// ---------------- final projection: fp32 output ----------------
__global__ void out_kernel(const float* __restrict__ ln, const float* __restrict__ W,
                           const float* __restrict__ bias, float* __restrict__ out)
{
    int idx = threadIdx.x;                           // 192 threads, 1 block
    if (idx >= BATCH*3) return;
    int b = idx / 3, e = idx % 3;
    float s = bias[e];
    const float* xr = ln + ((size_t)(b*SEQ + SEQ-1))*128;
    for (int d = 0; d < 128; ++d) s += xr[d]*W[d*3+e];
    out[idx] = s;
}

#define LCHK do { \
    if (hipGetLastError() != hipSuccess){ \
        sentinel_kernel<<<1, 192, 0, stream>>>((float*)d_out, 3000.0f + 32.0f*(float)launch_idx); \
        return; } \
    ++launch_idx; } while(0)

extern "C" void kernel_launch(void* const* d_in, const int* in_sizes, int n_in,
                              void* d_out, int out_size, void* d_ws, size_t ws_size,
                              hipStream_t stream)
{
    (void)out_size;
    static const int expected_sizes[30] = {
        49152, 384, 128, 512, 262144, 4096, 1024, 4096, 4096, 4096,
        12288, 16, 12288, 16, 1024, 1024, 131072, 256, 1024, 256,
        32768, 1024, 32768, 256, 256, 98304, 49152, 128, 384, 3
    };
    if (n_in != 30){ sentinel_kernel<<<1,192,0,stream>>>((float*)d_out, 5000.0f); return; }
    for (int i = 0; i < 30; ++i)
        if (in_sizes[i] != expected_sizes[i]){
            sentinel_kernel<<<1,192,0,stream>>>((float*)d_out, 2000.0f + 32.0f*i); return; }
    if (ws_size < (size_t)96*1024*1024){
        sentinel_kernel<<<1,192,0,stream>>>((float*)d_out, 1000.0f + (float)(ws_size >> 20)); return; }

    const float* x        = (const float*)d_in[0];
    const float* W_emb    = (const float*)d_in[1];
    const float* b_emb    = (const float*)d_in[2];
    const float* m_ln_w   = (const float*)d_in[3];
    const float* m_Wup    = (const float*)d_in[4];
    const float* m_conv_w = (const float*)d_in[5];
    const float* m_conv_b = (const float*)d_in[6];
    const float* m_Wq     = (const float*)d_in[7];
    const float* m_Wk     = (const float*)d_in[8];
    const float* m_Wv     = (const float*)d_in[9];
    const float* m_Wig    = (const float*)d_in[10];
    const float* m_big    = (const float*)d_in[11];
    const float* m_Wfg    = (const float*)d_in[12];
    const float* m_bfg    = (const float*)d_in[13];
    const float* m_gn_w   = (const float*)d_in[14];
    const float* m_skip   = (const float*)d_in[15];
    const float* m_Wdown  = (const float*)d_in[16];
    const float* s_ln_w   = (const float*)d_in[17];
    const float* s_conv_w = (const float*)d_in[18];
    const float* s_conv_b = (const float*)d_in[19];
    const float* s_Wg     = (const float*)d_in[20];
    const float* s_bg     = (const float*)d_in[21];
    const float* s_R      = (const float*)d_in[22];
    const float* s_gn_w   = (const float*)d_in[23];
    const float* s_ln2_w  = (const float*)d_in[24];
    const float* s_Wff_up = (const float*)d_in[25];
    const float* s_Wff_dn = (const float*)d_in[26];
    const float* post_ln  = (const float*)d_in[27];
    const float* W_out    = (const float*)d_in[28];
    const float* b_out    = (const float*)d_in[29];

    float* ws  = (float*)d_ws;
    float* h   = ws;                         // T*128
    float* ln  = h   + (size_t)T_TOK*128;    // T*128; igt/fgt/cs/pm alias (ln dead then)
    float* up  = ln  + (size_t)T_TOK*128;    // T*512
    float* xc  = up  + (size_t)T_TOK*512;    // T*256
    float* qb  = xc  + (size_t)T_TOK*256;    // T*256
    float* kb  = qb  + (size_t)T_TOK*256;    // T*256 (k; sLSTM ys)
    float* igt  = ln;
    float* fgt  = ln + 65536;
    float* csb  = ln + 2*65536;
    float* pmb  = ln + 3*65536;

    int launch_idx = 0;
    (void)hipGetLastError();

    embed_kernel<<<(T_TOK*128)/256, 256, 0, stream>>>(x, W_emb, b_emb, h); LCHK;

    const char* bt = "msmsmm";
    int mi = 0, si = 0;
    for (int blk = 0; blk < 6; ++blk){
        if (bt[blk] == 'm'){
            ln_kernel<<<T_TOK, 64, 0, stream>>>(h, m_ln_w + mi*128, ln); LCHK;
            gemm_tiled_kernel<<<(T_TOK/TM)*(512/TN), 256, 0, stream>>>(ln, m_Wup + (size_t)mi*65536, up, T_TOK, 512, 128, 0); LCHK;
            conv_silu_kernel<<<(T_TOK*256)/256, 256, 0, stream>>>(up, 512, m_conv_w + mi*1024, m_conv_b + mi*256, xc, 256); LCHK;
            headwise_kernel<<<(T_TOK*256)/256, 256, 0, stream>>>(xc, 256, m_Wq + mi*1024, qb); LCHK;
            headwise_kernel<<<(T_TOK*256)/256, 256, 0, stream>>>(xc, 256, m_Wk + mi*1024, kb); LCHK;
            headwise_inplace_kernel<<<(T_TOK*64)/256, 256, 0, stream>>>(up, m_Wv + mi*1024); LCHK;
            gateproj_kernel<<<T_TOK/4, 256, 0, stream>>>(qb, kb, up, m_Wig + mi*3072, m_big + mi*4,
                                                         m_Wfg + mi*3072, m_bfg + mi*4, igt, fgt); LCHK;
            cs_kernel<<<BATCH*NH, 64, 0, stream>>>(fgt, igt, csb, pmb); LCHK;
            attn_kernel<<<BATCH*NH*2, 256, 0, stream>>>(qb, kb, up, igt, csb, pmb); LCHK;
            mh_gate_kernel<<<(T_TOK*4)/256, 256, 0, stream>>>(qb, up, xc, m_gn_w + mi*256, m_skip + mi*256); LCHK;
            gemm_tiled_kernel<<<(T_TOK/TM)*(128/TN), 256, 0, stream>>>(qb, m_Wdown + (size_t)mi*32768, h, T_TOK, 128, 256, 1); LCHK;
            ++mi;
        } else {
            ln_kernel<<<T_TOK, 64, 0, stream>>>(h, s_ln_w + si*128, ln); LCHK;
            conv_silu_kernel<<<(T_TOK*128)/256, 256, 0, stream>>>(ln, 128, s_conv_w + si*512, s_conv_b + si*128, xc, 128); LCHK;
            slstm_gates_kernel<<<T_TOK/SG_TOK, 512, 0, stream>>>(xc, ln, s_Wg + si*16384, s_bg + si*512, up); LCHK;
            slstm_scan_kernel<<<BATCH*4, 64, 0, stream>>>(up, s_R + si*16384, kb); LCHK;
            mh_add_kernel<<<(T_TOK*4)/256, 256, 0, stream>>>(kb, s_gn_w + si*128, h); LCHK;
            ln_kernel<<<T_TOK, 64, 0, stream>>>(h, s_ln2_w + si*128, ln); LCHK;
            gemm_tiled_kernel<<<(T_TOK/TM)*(384/TN), 256, 0, stream>>>(ln, s_Wff_up + (size_t)si*49152, up, T_TOK, 384, 128, 0); LCHK;
            geluv_kernel<<<(T_TOK*192)/256, 256, 0, stream>>>(up, qb); LCHK;
            gemm_tiled_kernel<<<(T_TOK/TM)*(128/TN), 256, 0, stream>>>(qb, s_Wff_dn + (size_t)si*24576, h, T_TOK, 128, 192, 1); LCHK;
            ++si;
        }
    }

    ln_kernel<<<T_TOK, 64, 0, stream>>>(h, post_ln, ln); LCHK;
    out_kernel<<<1, 192, 0, stream>>>(ln, W_out, b_out, (float*)d_out); LCHK;
}

// Round 9
// 1701.049 us; speedup vs baseline: 1.7855x; 1.7855x over previous
//
#include <hip/hip_runtime.h>
#include <hip/hip_bf16.h>

#define D_MODEL 128
#define INNER 256
#define NH 4
#define DHM 64
#define SNH 4
#define SDH 32
#define FF 192
#define CK 4
#define BATCH 64
#define SEQ 256
#define T_TOK (BATCH*SEQ)   /* 16384 tokens */

typedef __hip_bfloat16 bf16;

__device__ __forceinline__ float sigf(float x){ return 1.0f/(1.0f+__expf(-x)); }
__device__ __forceinline__ float bcast_lane(float v, int k){
    return __uint_as_float(__builtin_amdgcn_readlane(__float_as_uint(v), k));
}
__device__ __forceinline__ float frcp(float x){ return __builtin_amdgcn_rcpf(x); }

// ---------------- sentinel writer (fp32) ----------------
__global__ void sentinel_kernel(float* __restrict__ out, float v)
{
    int idx = threadIdx.x;
    if (idx < BATCH*3) out[idx] = v;
}

// ---------------- embed ----------------
__global__ void embed_kernel(const float* __restrict__ x, const float* __restrict__ W,
                             const float* __restrict__ bias, float* __restrict__ h)
{
    int idx = blockIdx.x*blockDim.x + threadIdx.x;   // T*128
    if (idx >= T_TOK*D_MODEL) return;
    int d = idx & 127; int t = idx >> 7;
    float s = bias[d];
    #pragma unroll
    for (int i = 0; i < 3; ++i) s += x[t*3+i] * W[i*D_MODEL+d];
    h[idx] = s;
}

// ---------------- LN: one WAVE (64 threads) per token, coalesced ----------------
__global__ void ln_kernel(const float* __restrict__ x, const float* __restrict__ w,
                          float* __restrict__ out)
{
    int t = blockIdx.x; int lane = threadIdx.x;      // 64 threads
    float v0 = x[(size_t)t*128 + lane], v1 = x[(size_t)t*128 + 64 + lane];
    float s = v0 + v1, ss = v0*v0 + v1*v1;
    #pragma unroll
    for (int off = 32; off >= 1; off >>= 1){ s += __shfl_xor(s,off); ss += __shfl_xor(ss,off); }
    float mu  = s * (1.f/128.f);
    float var = fmaxf(ss * (1.f/128.f) - mu*mu, 0.f);
    float r   = rsqrtf(var + 1e-6f);
    out[(size_t)t*128 + lane]      = (v0-mu)*r*w[lane];
    out[(size_t)t*128 + 64 + lane] = (v1-mu)*r*w[64+lane];
}

// ---------------- tiled GEMM 64x64: C[M,N] (+)= A[M,K] * W[K,N] ----------------
#define TM 64
#define TN 64
#define TK 32
__global__ void __launch_bounds__(256)
gemm_tiled_kernel(const float* __restrict__ A, const float* __restrict__ W,
                  float* __restrict__ C, int M, int N, int Kd, int acc)
{
    int ntiles = N / TN;
    int bx = blockIdx.x % ntiles;
    int by = blockIdx.x / ntiles;
    __shared__ float As[TK][TM+1];   // +1 pad: kills 32-way write conflicts
    __shared__ float Ws[TK][TN];
    int tid = threadIdx.x;
    int tn = (tid & 15) * 4;         // col within tile
    int tm = (tid >> 4) * 4;         // row within tile
    float accr[4][4] = {{0.f}};
    for (int k0 = 0; k0 < Kd; k0 += TK){
        #pragma unroll
        for (int i = tid; i < TM*TK; i += 256){
            int c2 = i & 31, r = i >> 5;             // k fastest -> coalesced global
            As[c2][r] = A[(size_t)(by*TM + r)*Kd + k0 + c2];
        }
        #pragma unroll
        for (int i = tid; i < TK*TN; i += 256){
            int c2 = i & 63, r = i >> 6;             // n fastest -> coalesced global
            Ws[r][c2] = W[(size_t)(k0 + r)*N + bx*TN + c2];
        }
        __syncthreads();
        #pragma unroll
        for (int k = 0; k < TK; ++k){
            float a0 = As[k][tm], a1 = As[k][tm+1], a2 = As[k][tm+2], a3 = As[k][tm+3];
            float4 wv = *(const float4*)&Ws[k][tn];
            accr[0][0] = fmaf(a0, wv.x, accr[0][0]); accr[0][1] = fmaf(a0, wv.y, accr[0][1]);
            accr[0][2] = fmaf(a0, wv.z, accr[0][2]); accr[0][3] = fmaf(a0, wv.w, accr[0][3]);
            accr[1][0] = fmaf(a1, wv.x, accr[1][0]); accr[1][1] = fmaf(a1, wv.y, accr[1][1]);
            accr[1][2] = fmaf(a1, wv.z, accr[1][2]); accr[1][3] = fmaf(a1, wv.w, accr[1][3]);
            accr[2][0] = fmaf(a2, wv.x, accr[2][0]); accr[2][1] = fmaf(a2, wv.y, accr[2][1]);
            accr[2][2] = fmaf(a2, wv.z, accr[2][2]); accr[2][3] = fmaf(a2, wv.w, accr[2][3]);
            accr[3][0] = fmaf(a3, wv.x, accr[3][0]); accr[3][1] = fmaf(a3, wv.y, accr[3][1]);
            accr[3][2] = fmaf(a3, wv.z, accr[3][2]); accr[3][3] = fmaf(a3, wv.w, accr[3][3]);
        }
        __syncthreads();
    }
    #pragma unroll
    for (int i = 0; i < 4; ++i){
        size_t off = (size_t)(by*TM + tm + i)*N + bx*TN + tn;
        if (acc){
            float4 old = *(float4*)&C[off];
            old.x += accr[i][0]; old.y += accr[i][1];
            old.z += accr[i][2]; old.w += accr[i][3];
            *(float4*)&C[off] = old;
        } else {
            *(float4*)&C[off] = make_float4(accr[i][0], accr[i][1], accr[i][2], accr[i][3]);
        }
    }
}

// ---------------- causal conv (K=4) + silu ----------------
__global__ void conv_silu_kernel(const float* __restrict__ in, int istride,
                                 const float* __restrict__ w, const float* __restrict__ bias,
                                 float* __restrict__ out, int C)
{
    int idx = blockIdx.x*blockDim.x + threadIdx.x;   // T*C
    if (idx >= T_TOK*C) return;
    int c = idx % C; int t = idx / C;
    int s = t & (SEQ-1); int b = t >> 8;
    float a = bias[c];
    int j0 = (s >= CK-1) ? s-(CK-1) : 0;
    for (int j = j0; j <= s; ++j){
        int k = j - s + (CK-1);
        a += in[(size_t)(b*SEQ+j)*istride + c] * w[c*CK + k];
    }
    out[idx] = a * sigf(a);
}

// ---------------- headwise 4x4 projection: q and k fused (xc read once) ----------
__global__ void headwise_qk_kernel(const float* __restrict__ xc,
                                   const float* __restrict__ Wq, const float* __restrict__ Wk,
                                   float* __restrict__ qout, float* __restrict__ kout)
{
    int idx = blockIdx.x*blockDim.x + threadIdx.x;   // T*256
    if (idx >= T_TOK*INNER) return;
    int c = idx & 255; int t = idx >> 8;
    int n = c >> 2, l = c & 3;
    const float* xr = xc + (size_t)t*256 + n*4;
    float x0 = xr[0], x1 = xr[1], x2 = xr[2], x3 = xr[3];
    const float* wq = Wq + n*16 + l;
    const float* wk = Wk + n*16 + l;
    qout[idx] = x0*wq[0] + x1*wq[4] + x2*wq[8] + x3*wq[12];
    kout[idx] = x0*wk[0] + x1*wk[4] + x2*wk[8] + x3*wk[12];
}

__global__ void headwise_inplace_kernel(float* __restrict__ up, const float* __restrict__ W)
{
    int idx = blockIdx.x*blockDim.x + threadIdx.x;   // T*64
    if (idx >= T_TOK*64) return;
    int n = idx & 63; int t = idx >> 6;
    float* xr = up + (size_t)t*512 + n*4;
    float x0 = xr[0], x1 = xr[1], x2 = xr[2], x3 = xr[3];
    const float* w = W + n*16;
    for (int l = 0; l < 4; ++l)
        xr[l] = x0*w[l] + x1*w[4+l] + x2*w[8+l] + x3*w[12+l];
}

// ---------------- ig/fg projection: one WAVE per token ---------------------------
__global__ void __launch_bounds__(256)
gateproj_kernel(const float* __restrict__ q, const float* __restrict__ k,
                const float* __restrict__ up,
                const float* __restrict__ Wig, const float* __restrict__ big,
                const float* __restrict__ Wfg, const float* __restrict__ bfg,
                float* __restrict__ igt, float* __restrict__ fgt)
{
    int t = blockIdx.x*4 + (threadIdx.x >> 6);       // token; 4 waves/block
    int lane = threadIdx.x & 63;
    float4 si = make_float4(0.f,0.f,0.f,0.f);
    float4 sf = make_float4(0.f,0.f,0.f,0.f);
    #pragma unroll
    for (int c = 0; c < 12; ++c){
        int j = c*64 + lane;
        float xv;
        if (c < 4)      xv = q[(size_t)t*256 + j];
        else if (c < 8) xv = k[(size_t)t*256 + j - 256];
        else            xv = up[(size_t)t*512 + j - 512];   // v in up[:, :256]
        float4 wi = *(const float4*)(Wig + (size_t)j*4);
        float4 wf = *(const float4*)(Wfg + (size_t)j*4);
        si.x = fmaf(xv, wi.x, si.x); si.y = fmaf(xv, wi.y, si.y);
        si.z = fmaf(xv, wi.z, si.z); si.w = fmaf(xv, wi.w, si.w);
        sf.x = fmaf(xv, wf.x, sf.x); sf.y = fmaf(xv, wf.y, sf.y);
        sf.z = fmaf(xv, wf.z, sf.z); sf.w = fmaf(xv, wf.w, sf.w);
    }
    #pragma unroll
    for (int off = 32; off >= 1; off >>= 1){
        si.x += __shfl_xor(si.x, off); si.y += __shfl_xor(si.y, off);
        si.z += __shfl_xor(si.z, off); si.w += __shfl_xor(si.w, off);
        sf.x += __shfl_xor(sf.x, off); sf.y += __shfl_xor(sf.y, off);
        sf.z += __shfl_xor(sf.z, off); sf.w += __shfl_xor(sf.w, off);
    }
    int b = t >> 8, s = t & 255;
    int hh = lane & 3;
    float vi = (hh==0) ? si.x : (hh==1) ? si.y : (hh==2) ? si.z : si.w;
    float vf = (hh==0) ? sf.x : (hh==1) ? sf.y : (hh==2) ? sf.z : sf.w;
    if (lane < 4)       igt[(b*4+hh)*SEQ + s] = vi + big[hh];
    else if (lane < 8)  fgt[(b*4+hh)*SEQ + s] = vf + bfg[hh];
}

// ---------------- cs: one WAVE per (b,h), parallel logsigmoid + wave scan --------
__global__ void __launch_bounds__(64)
cs_kernel(const float* __restrict__ fgt, const float* __restrict__ igt,
          float* __restrict__ cs, float* __restrict__ pm)
{
    int bh = blockIdx.x;                             // 256 blocks
    int lane = threadIdx.x;                          // 64
    float4 f4 = *(const float4*)(fgt + (size_t)bh*SEQ + lane*4);
    float4 i4 = *(const float4*)(igt + (size_t)bh*SEQ + lane*4);
    float lf0, lf1, lf2, lf3;
    { float f = f4.x; lf0 = (f > 0.f) ? -log1pf(__expf(-f)) : f - log1pf(__expf(f)); }
    { float f = f4.y; lf1 = (f > 0.f) ? -log1pf(__expf(-f)) : f - log1pf(__expf(f)); }
    { float f = f4.z; lf2 = (f > 0.f) ? -log1pf(__expf(-f)) : f - log1pf(__expf(f)); }
    { float f = f4.w; lf3 = (f > 0.f) ? -log1pf(__expf(-f)) : f - log1pf(__expf(f)); }
    float p0 = lf0, p1 = p0 + lf1, p2 = p1 + lf2, p3 = p2 + lf3;
    float incl = p3;
    #pragma unroll
    for (int off = 1; off < 64; off <<= 1){
        float v = __shfl_up(incl, off);
        if (lane >= off) incl += v;
    }
    float excl = __shfl_up(incl, 1);
    if (lane == 0) excl = 0.f;
    float c0 = excl + p0, c1 = excl + p1, c2 = excl + p2, c3 = excl + p3;
    *(float4*)(cs + (size_t)bh*SEQ + lane*4) = make_float4(c0, c1, c2, c3);
    float u0 = i4.x - c0, u1 = i4.y - c1, u2 = i4.z - c2, u3 = i4.w - c3;
    float m0 = u0, m1 = fmaxf(m0, u1), m2 = fmaxf(m1, u2), m3 = fmaxf(m2, u3);
    float inm = m3;
    #pragma unroll
    for (int off = 1; off < 64; off <<= 1){
        float v = __shfl_up(inm, off);
        if (lane >= off) inm = fmaxf(inm, v);
    }
    float exm = __shfl_up(inm, 1);
    if (lane == 0) exm = -1e30f;
    *(float4*)(pm + (size_t)bh*SEQ + lane*4) =
        make_float4(fmaxf(exm, m0), fmaxf(exm, m1), fmaxf(exm, m2), fmaxf(exm, m3));
}

// ---------------- attention (round-7 version, measured 121us): Q-tiles, no
// min-occupancy bound. Round-8 lesson (3rd spill): this structure supports at
// most ~64 Q-floats/lane; 2-row variant (128) spilled 1.15 GB at the 256-VGPR cap.
#define AC 32
#define QB 64
__global__ void __launch_bounds__(256)
attn_kernel(float* __restrict__ q, const float* __restrict__ kk,
            const float* __restrict__ up,
            const float* __restrict__ igt, const float* __restrict__ cs,
            const float* __restrict__ pm)
{
    __shared__ float k_sh[AC][DHM];      // 8 KB
    __shared__ float v_sh[AC][DHM];      // 8 KB
    __shared__ float S_sh[QB][33];       // 8.4 KB
    __shared__ float u_sh[SEQ];          // 1 KB
    int blk = blockIdx.x;                // bh*4 + qt
    int bh = blk >> 2, qt = blk & 3;
    int b = bh >> 2, hh = bh & 3;
    int tid = threadIdx.x;
    int il = tid & 63;                   // local row
    int g = tid >> 6;                    // 0..3: phase1 j-eighth; phase2 d-quarter
    int i = qt*QB + il;                  // global row
    u_sh[tid] = igt[bh*SEQ + tid] - cs[bh*SEQ + tid];
    float csi = cs[bh*SEQ + i];
    float m   = csi + pm[bh*SEQ + i];
    const float4* qp4 = (const float4*)(q + ((size_t)(b*SEQ + i)*INNER + hh*DHM));
    float4 qr4[16];
    #pragma unroll
    for (int r = 0; r < 16; ++r) qr4[r] = qp4[r];
    float4 acc4[4];
    #pragma unroll
    for (int r = 0; r < 4; ++r) acc4[r] = make_float4(0.f,0.f,0.f,0.f);
    float ssum = 0.f;
    int cend = (qt+1)*QB;

    for (int c0 = 0; c0 < cend; c0 += AC){
        // stage K/V chunk: 256 threads cover 2*32*16 float4 (4 each)
        {
            int half = tid >> 7;         // 0: K  1: V
            int idx2 = tid & 127;
            int r0 = idx2 >> 4;          // 0..7
            int d4 = idx2 & 15;
            #pragma unroll
            for (int rr = 0; rr < 4; ++rr){
                int r = r0 + rr*8;
                size_t tj = (size_t)(b*SEQ + c0 + r);
                if (half == 0)
                    ((float4*)&k_sh[r][0])[d4] = *(const float4*)(kk + tj*INNER + hh*DHM + d4*4);
                else
                    ((float4*)&v_sh[r][0])[d4] = *(const float4*)(up + tj*512 + hh*DHM + d4*4);
            }
        }
        __syncthreads();
        if (i >= c0){
            // phase1: 8 dots, masked, scaled, exp'd -> S_sh[il][g*8 + jj]
            #pragma unroll
            for (int jj = 0; jj < 8; ++jj){
                int jl = g*8 + jj;
                const float4* kr = (const float4*)&k_sh[jl][0];
                float d0=0.f, d1=0.f, d2=0.f, d3=0.f;
                #pragma unroll
                for (int r4 = 0; r4 < 4; ++r4){
                    float4 ka = kr[r4*4+0], kb2 = kr[r4*4+1];
                    float4 kc = kr[r4*4+2], kd  = kr[r4*4+3];
                    float4 qa = qr4[r4*4+0], qb2 = qr4[r4*4+1];
                    float4 qc = qr4[r4*4+2], qd  = qr4[r4*4+3];
                    d0 += qa.x*ka.x + qa.y*ka.y + qa.z*ka.z + qa.w*ka.w;
                    d1 += qb2.x*kb2.x + qb2.y*kb2.y + qb2.z*kb2.z + qb2.w*kb2.w;
                    d2 += qc.x*kc.x + qc.y*kc.y + qc.z*kc.z + qc.w*kc.w;
                    d3 += qd.x*kd.x + qd.y*kd.y + qd.z*kd.z + qd.w*kd.w;
                }
                float dot = (d0+d1) + (d2+d3);
                int jg = c0 + jl;
                float arg = fminf(csi + u_sh[jg] - m, 0.f);
                S_sh[il][jl] = (jg <= i) ? dot * 0.125f * __expf(arg) : 0.f;
            }
        }
        __syncthreads();
        if (i >= c0){
            // phase2: accumulate 16 output dims over the chunk's 32 j's
            #pragma unroll
            for (int jj = 0; jj < AC; ++jj){
                float sv = S_sh[il][jj];
                ssum += sv;
                const float4* vr = (const float4*)&v_sh[jj][g*16];
                #pragma unroll
                for (int r = 0; r < 4; ++r){
                    float4 vv = vr[r];
                    acc4[r].x += sv*vv.x; acc4[r].y += sv*vv.y;
                    acc4[r].z += sv*vv.z; acc4[r].w += sv*vv.w;
                }
            }
        }
        __syncthreads();
    }
    float nrm = fmaxf(fabsf(ssum), __expf(-m)) + 1e-6f;
    float rn = 1.f/nrm;
    float4* op = (float4*)(q + ((size_t)(b*SEQ + i)*INNER + hh*DHM + g*16));
    #pragma unroll
    for (int r = 0; r < 4; ++r){
        float4 o = acc4[r];
        o.x *= rn; o.y *= rn; o.z *= rn; o.w *= rn;
        op[r] = o;
    }
}

// ---------------- mh_gate v2: one WAVE per (t,h), coalesced ----------------------
// Was thread-per-(t,h): three serial 64-iter loops, lane stride 256B (64 cache
// lines per load). Now: lane = d, single coalesced pass, shfl_xor reduce.
__global__ void __launch_bounds__(256)
mh_gate_kernel(float* __restrict__ q, const float* __restrict__ up,
               const float* __restrict__ xc,
               const float* __restrict__ gnw, const float* __restrict__ skip)
{
    int unit = blockIdx.x*4 + (threadIdx.x >> 6);    // t*4 + hh
    int lane = threadIdx.x & 63;
    int t = unit >> 2, hh = unit & 3;
    int c = hh*DHM + lane;
    float v = q[(size_t)t*256 + c];
    float s = v, ss = v*v;
    #pragma unroll
    for (int off = 32; off >= 1; off >>= 1){ s += __shfl_xor(s,off); ss += __shfl_xor(ss,off); }
    float mu  = s * (1.f/64.f);
    float var = fmaxf(ss * (1.f/64.f) - mu*mu, 0.f);
    float r   = rsqrtf(var + 1e-6f);
    float hn  = (v-mu)*r*gnw[c];
    float z   = up[(size_t)t*512 + 256 + c];
    q[(size_t)t*256 + c] = (hn + skip[c]*xc[(size_t)t*256 + c]) * (z*sigf(z));
}

// ---------------- sLSTM gates: weight-stationary registers -----------------------
#define SG_TOK 16
__global__ void __launch_bounds__(512)
slstm_gates_kernel(const float* __restrict__ xc, const float* __restrict__ xl,
                   const float* __restrict__ Wg, const float* __restrict__ bg,
                   float* __restrict__ gates)
{
    int tid = threadIdx.x;
    int l  = tid & 31;
    int gn = tid >> 5;            // g*4+n
    int g  = gn >> 2, n = gn & 3;
    int t0 = blockIdx.x * SG_TOK;
    float wr[32];
    #pragma unroll
    for (int k = 0; k < 32; ++k) wr[k] = Wg[(size_t)gn*1024 + k*32 + l];
    float bias = bg[g*128 + n*32 + l];
    const float* xin = (g < 2) ? xc : xl;
    #pragma unroll 4
    for (int t = 0; t < SG_TOK; ++t){
        int tok = t0 + t;
        const float4* xr = (const float4*)(xin + (size_t)tok*128 + n*32);
        float a = bias;
        #pragma unroll
        for (int k4 = 0; k4 < 8; ++k4){
            float4 xv = xr[k4];
            a = fmaf(xv.x, wr[k4*4+0], a);
            a = fmaf(xv.y, wr[k4*4+1], a);
            a = fmaf(xv.z, wr[k4*4+2], a);
            a = fmaf(xv.w, wr[k4*4+3], a);
        }
        int b = tok >> 8, s = tok & 255;
        gates[(size_t)((b*4+n)*SEQ + s)*128 + l*4 + g] = a;
    }
}

// ---------------- sLSTM recurrence: shortened critical path ----------------------
__global__ void __launch_bounds__(64)
slstm_scan_kernel(const float* __restrict__ gates, const float* __restrict__ Rw,
                  float* __restrict__ ys)
{
    int bn = blockIdx.x;                 // b*4 + n
    int b = bn >> 2, n = bn & 3;
    int lane = threadIdx.x;              // 0..63
    int l = lane & 31;
    int hi = lane >> 5;                  // 0: gates i,f   1: gates z,o
    int gA = hi ? 2 : 0, gB = hi ? 3 : 1;
    const float* Rbase = Rw + (size_t)n*1024 + l;
    float Ra[32], Rb[32];
    #pragma unroll
    for (int k = 0; k < 32; ++k){
        Ra[k] = Rbase[(size_t)gA*4096 + k*32];
        Rb[k] = Rbase[(size_t)gB*4096 + k*32];
    }
    const float* gbase = gates + (size_t)bn*SEQ*128 + l*4 + (hi ? 2 : 0);
    float* yrow = ys + (size_t)b*SEQ*128 + n*32 + l;
    float2 g0 = *(const float2*)(gbase);
    float2 g1 = *(const float2*)(gbase + 128);
    float c = 0.f, nst = 0.f, m = 0.f, hst = 0.f;
    for (int s = 0; s < SEQ; ++s){
        float2 g2 = (s+2 < SEQ) ? *(const float2*)(gbase + (size_t)(s+2)*128)
                                : make_float2(0.f, 0.f);
        float ra0=0.f, ra1=0.f, ra2=0.f, ra3=0.f;
        float rb0=0.f, rb1=0.f, rb2=0.f, rb3=0.f;
        #pragma unroll
        for (int k = 0; k < 8; ++k){
            float h0 = bcast_lane(hst, k);
            float h1 = bcast_lane(hst, k+8);
            float h2 = bcast_lane(hst, k+16);
            float h3 = bcast_lane(hst, k+24);
            ra0 = fmaf(h0, Ra[k],    ra0); rb0 = fmaf(h0, Rb[k],    rb0);
            ra1 = fmaf(h1, Ra[k+8],  ra1); rb1 = fmaf(h1, Rb[k+8],  rb1);
            ra2 = fmaf(h2, Ra[k+16], ra2); rb2 = fmaf(h2, Rb[k+16], rb2);
            ra3 = fmaf(h3, Ra[k+24], ra3); rb3 = fmaf(h3, Rb[k+24], rb3);
        }
        float ra = (ra0+ra1) + (ra2+ra3);
        float rb = (rb0+rb1) + (rb2+rb3);
        float pa = g0.x + ra;            // lo: ir   hi: zr
        float pb = g0.y + rb;            // lo: fr   hi: orr
        float zr  = __shfl_xor(pa, 32);
        float orr = __shfl_xor(pb, 32);
        float mnew = fmaxf(pb + m, pa);
        float iv = __expf(pa - mnew);
        float fv = __expf(pb + m - mnew);
        float zt = 1.f - 2.f*frcp(1.f + __expf(2.f*zr));
        float ov = frcp(1.f + __expf(-orr));
        c   = fv*c + iv*zt;
        nst = fv*nst + iv;
        hst = ov * c * frcp(nst + 1e-8f);
        m = mnew;
        if (!hi) yrow[(size_t)s*128] = hst;
        g0 = g1; g1 = g2;
    }
}

// ---------------- mh_add v2: 32-lane group per (t,n), coalesced ------------------
__global__ void __launch_bounds__(256)
mh_add_kernel(const float* __restrict__ ys, const float* __restrict__ gnw,
              float* __restrict__ h)
{
    int unit = blockIdx.x*8 + (threadIdx.x >> 5);    // t*4 + n
    int l = threadIdx.x & 31;
    int t = unit >> 2, n = unit & 3;
    float v = ys[(size_t)t*128 + n*32 + l];
    float s = v, ss = v*v;
    #pragma unroll
    for (int off = 16; off >= 1; off >>= 1){ s += __shfl_xor(s,off); ss += __shfl_xor(ss,off); }
    float mu  = s * (1.f/32.f);
    float var = fmaxf(ss * (1.f/32.f) - mu*mu, 0.f);
    float r   = rsqrtf(var + 1e-6f);
    h[(size_t)t*128 + n*32 + l] += (v-mu)*r*gnw[n*32+l];
}

__global__ void geluv_kernel(const float* __restrict__ up, float* __restrict__ out)
{
    int idx = blockIdx.x*blockDim.x + threadIdx.x;   // T*192
    if (idx >= T_TOK*FF) return;
    int j = idx % FF; int t = idx / FF;
    float g  = up[(size_t)t*384 + j];
    float vv = up[(size_t)t*384 + FF + j];
    float gel = 0.5f*g*(1.f + tanhf(0.7978845608028654f*(g + 0.044715f*g*g*g)));
    out[idx] = gel*vv;
}

// ---------------- final projection: fp32 output ----------------
__global__ void out_kernel(const float* __restrict__ ln, const float* __restrict__ W,
                           const float* __restrict__ bias, float* __restrict__ out)
{
    int idx = threadIdx.x;                           // 192 threads, 1 block
    if (idx >= BATCH*3) return;
    int b = idx / 3, e = idx % 3;
    float s = bias[e];
    const float* xr = ln + ((size_t)(b*SEQ + SEQ-1))*128;
    for (int d = 0; d < 128; ++d) s += xr[d]*W[d*3+e];
    out[idx] = s;
}

#define LCHK do { \
    if (hipGetLastError() != hipSuccess){ \
        sentinel_kernel<<<1, 192, 0, stream>>>((float*)d_out, 3000.0f + 32.0f*(float)launch_idx); \
        return; } \
    ++launch_idx; } while(0)

extern "C" void kernel_launch(void* const* d_in, const int* in_sizes, int n_in,
                              void* d_out, int out_size, void* d_ws, size_t ws_size,
                              hipStream_t stream)
{
    (void)out_size;
    static const int expected_sizes[30] = {
        49152, 384, 128, 512, 262144, 4096, 1024, 4096, 4096, 4096,
        12288, 16, 12288, 16, 1024, 1024, 131072, 256, 1024, 256,
        32768, 1024, 32768, 256, 256, 98304, 49152, 128, 384, 3
    };
    if (n_in != 30){ sentinel_kernel<<<1,192,0,stream>>>((float*)d_out, 5000.0f); return; }
    for (int i = 0; i < 30; ++i)
        if (in_sizes[i] != expected_sizes[i]){
            sentinel_kernel<<<1,192,0,stream>>>((float*)d_out, 2000.0f + 32.0f*i); return; }
    if (ws_size < (size_t)96*1024*1024){
        sentinel_kernel<<<1,192,0,stream>>>((float*)d_out, 1000.0f + (float)(ws_size >> 20)); return; }

    const float* x        = (const float*)d_in[0];
    const float* W_emb    = (const float*)d_in[1];
    const float* b_emb    = (const float*)d_in[2];
    const float* m_ln_w   = (const float*)d_in[3];
    const float* m_Wup    = (const float*)d_in[4];
    const float* m_conv_w = (const float*)d_in[5];
    const float* m_conv_b = (const float*)d_in[6];
    const float* m_Wq     = (const float*)d_in[7];
    const float* m_Wk     = (const float*)d_in[8];
    const float* m_Wv     = (const float*)d_in[9];
    const float* m_Wig    = (const float*)d_in[10];
    const float* m_big    = (const float*)d_in[11];
    const float* m_Wfg    = (const float*)d_in[12];
    const float* m_bfg    = (const float*)d_in[13];
    const float* m_gn_w   = (const float*)d_in[14];
    const float* m_skip   = (const float*)d_in[15];
    const float* m_Wdown  = (const float*)d_in[16];
    const float* s_ln_w   = (const float*)d_in[17];
    const float* s_conv_w = (const float*)d_in[18];
    const float* s_conv_b = (const float*)d_in[19];
    const float* s_Wg     = (const float*)d_in[20];
    const float* s_bg     = (const float*)d_in[21];
    const float* s_R      = (const float*)d_in[22];
    const float* s_gn_w   = (const float*)d_in[23];
    const float* s_ln2_w  = (const float*)d_in[24];
    const float* s_Wff_up = (const float*)d_in[25];
    const float* s_Wff_dn = (const float*)d_in[26];
    const float* post_ln  = (const float*)d_in[27];
    const float* W_out    = (const float*)d_in[28];
    const float* b_out    = (const float*)d_in[29];

    float* ws  = (float*)d_ws;
    float* h   = ws;                         // T*128
    float* ln  = h   + (size_t)T_TOK*128;    // T*128; igt/fgt/cs/pm alias (ln dead then)
    float* up  = ln  + (size_t)T_TOK*128;    // T*512
    float* xc  = up  + (size_t)T_TOK*512;    // T*256
    float* qb  = xc  + (size_t)T_TOK*256;    // T*256
    float* kb  = qb  + (size_t)T_TOK*256;    // T*256 (k; sLSTM ys)
    float* igt  = ln;
    float* fgt  = ln + 65536;
    float* csb  = ln + 2*65536;
    float* pmb  = ln + 3*65536;

    int launch_idx = 0;
    (void)hipGetLastError();

    embed_kernel<<<(T_TOK*128)/256, 256, 0, stream>>>(x, W_emb, b_emb, h); LCHK;

    const char* bt = "msmsmm";
    int mi = 0, si = 0;
    for (int blk = 0; blk < 6; ++blk){
        if (bt[blk] == 'm'){
            ln_kernel<<<T_TOK, 64, 0, stream>>>(h, m_ln_w + mi*128, ln); LCHK;
            gemm_tiled_kernel<<<(T_TOK/TM)*(512/TN), 256, 0, stream>>>(ln, m_Wup + (size_t)mi*65536, up, T_TOK, 512, 128, 0); LCHK;
            conv_silu_kernel<<<(T_TOK*256)/256, 256, 0, stream>>>(up, 512, m_conv_w + mi*1024, m_conv_b + mi*256, xc, 256); LCHK;
            headwise_qk_kernel<<<(T_TOK*256)/256, 256, 0, stream>>>(xc, m_Wq + mi*1024, m_Wk + mi*1024, qb, kb); LCHK;
            headwise_inplace_kernel<<<(T_TOK*64)/256, 256, 0, stream>>>(up, m_Wv + mi*1024); LCHK;
            gateproj_kernel<<<T_TOK/4, 256, 0, stream>>>(qb, kb, up, m_Wig + mi*3072, m_big + mi*4,
                                                         m_Wfg + mi*3072, m_bfg + mi*4, igt, fgt); LCHK;
            cs_kernel<<<BATCH*NH, 64, 0, stream>>>(fgt, igt, csb, pmb); LCHK;
            attn_kernel<<<BATCH*NH*4, 256, 0, stream>>>(qb, kb, up, igt, csb, pmb); LCHK;
            mh_gate_kernel<<<T_TOK, 256, 0, stream>>>(qb, up, xc, m_gn_w + mi*256, m_skip + mi*256); LCHK;
            gemm_tiled_kernel<<<(T_TOK/TM)*(128/TN), 256, 0, stream>>>(qb, m_Wdown + (size_t)mi*32768, h, T_TOK, 128, 256, 1); LCHK;
            ++mi;
        } else {
            ln_kernel<<<T_TOK, 64, 0, stream>>>(h, s_ln_w + si*128, ln); LCHK;
            conv_silu_kernel<<<(T_TOK*128)/256, 256, 0, stream>>>(ln, 128, s_conv_w + si*512, s_conv_b + si*128, xc, 128); LCHK;
            slstm_gates_kernel<<<T_TOK/SG_TOK, 512, 0, stream>>>(xc, ln, s_Wg + si*16384, s_bg + si*512, up); LCHK;
            slstm_scan_kernel<<<BATCH*4, 64, 0, stream>>>(up, s_R + si*16384, kb); LCHK;
            mh_add_kernel<<<T_TOK/2, 256, 0, stream>>>(kb, s_gn_w + si*128, h); LCHK;
            ln_kernel<<<T_TOK, 64, 0, stream>>>(h, s_ln2_w + si*128, ln); LCHK;
            gemm_tiled_kernel<<<(T_TOK/TM)*(384/TN), 256, 0, stream>>>(ln, s_Wff_up + (size_t)si*49152, up, T_TOK, 384, 128, 0); LCHK;
            geluv_kernel<<<(T_TOK*192)/256, 256, 0, stream>>>(up, qb); LCHK;
            gemm_tiled_kernel<<<(T_TOK/TM)*(128/TN), 256, 0, stream>>>(qb, s_Wff_dn + (size_t)si*24576, h, T_TOK, 128, 192, 1); LCHK;
            ++si;
        }
    }

    ln_kernel<<<T_TOK, 64, 0, stream>>>(h, post_ln, ln); LCHK;
    out_kernel<<<1, 192, 0, stream>>>(ln, W_out, b_out, (float*)d_out); LCHK;
}

// Round 10
// 1569.351 us; speedup vs baseline: 1.9353x; 1.0839x over previous
//
#include <hip/hip_runtime.h>
#include <hip/hip_bf16.h>

#define D_MODEL 128
#define INNER 256
#define NH 4
#define DHM 64
#define SNH 4
#define SDH 32
#define FF 192
#define CK 4
#define BATCH 64
#define SEQ 256
#define T_TOK (BATCH*SEQ)   /* 16384 tokens */

typedef __hip_bfloat16 bf16;

__device__ __forceinline__ float sigf(float x){ return 1.0f/(1.0f+__expf(-x)); }
__device__ __forceinline__ float bcast_lane(float v, int k){
    return __uint_as_float(__builtin_amdgcn_readlane(__float_as_uint(v), k));
}
__device__ __forceinline__ float frcp(float x){ return __builtin_amdgcn_rcpf(x); }

// ---------------- sentinel writer (fp32) ----------------
__global__ void sentinel_kernel(float* __restrict__ out, float v)
{
    int idx = threadIdx.x;
    if (idx < BATCH*3) out[idx] = v;
}

// ---------------- embed ----------------
__global__ void embed_kernel(const float* __restrict__ x, const float* __restrict__ W,
                             const float* __restrict__ bias, float* __restrict__ h)
{
    int idx = blockIdx.x*blockDim.x + threadIdx.x;   // T*128
    if (idx >= T_TOK*D_MODEL) return;
    int d = idx & 127; int t = idx >> 7;
    float s = bias[d];
    #pragma unroll
    for (int i = 0; i < 3; ++i) s += x[t*3+i] * W[i*D_MODEL+d];
    h[idx] = s;
}

// ---------------- LN: one WAVE (64 threads) per token, coalesced ----------------
__global__ void ln_kernel(const float* __restrict__ x, const float* __restrict__ w,
                          float* __restrict__ out)
{
    int t = blockIdx.x; int lane = threadIdx.x;      // 64 threads
    float v0 = x[(size_t)t*128 + lane], v1 = x[(size_t)t*128 + 64 + lane];
    float s = v0 + v1, ss = v0*v0 + v1*v1;
    #pragma unroll
    for (int off = 32; off >= 1; off >>= 1){ s += __shfl_xor(s,off); ss += __shfl_xor(ss,off); }
    float mu  = s * (1.f/128.f);
    float var = fmaxf(ss * (1.f/128.f) - mu*mu, 0.f);
    float r   = rsqrtf(var + 1e-6f);
    out[(size_t)t*128 + lane]      = (v0-mu)*r*w[lane];
    out[(size_t)t*128 + 64 + lane] = (v1-mu)*r*w[64+lane];
}

// ---------------- tiled GEMM 64x64: C[M,N] (+)= A[M,K] * W[K,N] ----------------
#define TM 64
#define TN 64
#define TK 32
__global__ void __launch_bounds__(256)
gemm_tiled_kernel(const float* __restrict__ A, const float* __restrict__ W,
                  float* __restrict__ C, int M, int N, int Kd, int acc)
{
    int ntiles = N / TN;
    int bx = blockIdx.x % ntiles;
    int by = blockIdx.x / ntiles;
    __shared__ float As[TK][TM+1];   // +1 pad: kills 32-way write conflicts
    __shared__ float Ws[TK][TN];
    int tid = threadIdx.x;
    int tn = (tid & 15) * 4;         // col within tile
    int tm = (tid >> 4) * 4;         // row within tile
    float accr[4][4] = {{0.f}};
    for (int k0 = 0; k0 < Kd; k0 += TK){
        #pragma unroll
        for (int i = tid; i < TM*TK; i += 256){
            int c2 = i & 31, r = i >> 5;             // k fastest -> coalesced global
            As[c2][r] = A[(size_t)(by*TM + r)*Kd + k0 + c2];
        }
        #pragma unroll
        for (int i = tid; i < TK*TN; i += 256){
            int c2 = i & 63, r = i >> 6;             // n fastest -> coalesced global
            Ws[r][c2] = W[(size_t)(k0 + r)*N + bx*TN + c2];
        }
        __syncthreads();
        #pragma unroll
        for (int k = 0; k < TK; ++k){
            float a0 = As[k][tm], a1 = As[k][tm+1], a2 = As[k][tm+2], a3 = As[k][tm+3];
            float4 wv = *(const float4*)&Ws[k][tn];
            accr[0][0] = fmaf(a0, wv.x, accr[0][0]); accr[0][1] = fmaf(a0, wv.y, accr[0][1]);
            accr[0][2] = fmaf(a0, wv.z, accr[0][2]); accr[0][3] = fmaf(a0, wv.w, accr[0][3]);
            accr[1][0] = fmaf(a1, wv.x, accr[1][0]); accr[1][1] = fmaf(a1, wv.y, accr[1][1]);
            accr[1][2] = fmaf(a1, wv.z, accr[1][2]); accr[1][3] = fmaf(a1, wv.w, accr[1][3]);
            accr[2][0] = fmaf(a2, wv.x, accr[2][0]); accr[2][1] = fmaf(a2, wv.y, accr[2][1]);
            accr[2][2] = fmaf(a2, wv.z, accr[2][2]); accr[2][3] = fmaf(a2, wv.w, accr[2][3]);
            accr[3][0] = fmaf(a3, wv.x, accr[3][0]); accr[3][1] = fmaf(a3, wv.y, accr[3][1]);
            accr[3][2] = fmaf(a3, wv.z, accr[3][2]); accr[3][3] = fmaf(a3, wv.w, accr[3][3]);
        }
        __syncthreads();
    }
    #pragma unroll
    for (int i = 0; i < 4; ++i){
        size_t off = (size_t)(by*TM + tm + i)*N + bx*TN + tn;
        if (acc){
            float4 old = *(float4*)&C[off];
            old.x += accr[i][0]; old.y += accr[i][1];
            old.z += accr[i][2]; old.w += accr[i][3];
            *(float4*)&C[off] = old;
        } else {
            *(float4*)&C[off] = make_float4(accr[i][0], accr[i][1], accr[i][2], accr[i][3]);
        }
    }
}

// ---------------- tiled GEMM 128x64: 8x4 outputs/thread, for N>=384 K=128 --------
// 32 FMA per 3 ds_read_b128 (vs 16 per 2 in 64x64) and half the A-staging per
// output. Same k accumulation order -> bit-identical results.
#define HM 128
#define HN 64
#define HK 32
__global__ void __launch_bounds__(256)
gemm_tiled_m128_kernel(const float* __restrict__ A, const float* __restrict__ W,
                       float* __restrict__ C, int M, int N, int Kd, int acc)
{
    int ntiles = N / HN;
    int bx = blockIdx.x % ntiles;
    int by = blockIdx.x / ntiles;
    __shared__ float As[HK][HM+4];   // stride 132: float4-aligned rows
    __shared__ float Ws[HK][HN];
    int tid = threadIdx.x;
    int tn = (tid & 15) * 4;         // col within tile
    int tm = (tid >> 4) * 8;         // row within tile
    float accr[8][4] = {{0.f}};
    for (int k0 = 0; k0 < Kd; k0 += HK){
        #pragma unroll
        for (int i = tid; i < HM*HK; i += 256){
            int c2 = i & 31, r = i >> 5;             // k fastest -> coalesced global
            As[c2][r] = A[(size_t)(by*HM + r)*Kd + k0 + c2];
        }
        #pragma unroll
        for (int i = tid; i < HK*HN; i += 256){
            int c2 = i & 63, r = i >> 6;             // n fastest -> coalesced global
            Ws[r][c2] = W[(size_t)(k0 + r)*N + bx*HN + c2];
        }
        __syncthreads();
        #pragma unroll
        for (int k = 0; k < HK; ++k){
            float4 a0 = *(const float4*)&As[k][tm];
            float4 a1 = *(const float4*)&As[k][tm+4];
            float4 wv = *(const float4*)&Ws[k][tn];
            float av[8] = {a0.x,a0.y,a0.z,a0.w,a1.x,a1.y,a1.z,a1.w};
            #pragma unroll
            for (int ii = 0; ii < 8; ++ii){
                accr[ii][0] = fmaf(av[ii], wv.x, accr[ii][0]);
                accr[ii][1] = fmaf(av[ii], wv.y, accr[ii][1]);
                accr[ii][2] = fmaf(av[ii], wv.z, accr[ii][2]);
                accr[ii][3] = fmaf(av[ii], wv.w, accr[ii][3]);
            }
        }
        __syncthreads();
    }
    #pragma unroll
    for (int i = 0; i < 8; ++i){
        size_t off = (size_t)(by*HM + tm + i)*N + bx*HN + tn;
        if (acc){
            float4 old = *(float4*)&C[off];
            old.x += accr[i][0]; old.y += accr[i][1];
            old.z += accr[i][2]; old.w += accr[i][3];
            *(float4*)&C[off] = old;
        } else {
            *(float4*)&C[off] = make_float4(accr[i][0], accr[i][1], accr[i][2], accr[i][3]);
        }
    }
}

// ---------------- causal conv (K=4) + silu ----------------
__global__ void conv_silu_kernel(const float* __restrict__ in, int istride,
                                 const float* __restrict__ w, const float* __restrict__ bias,
                                 float* __restrict__ out, int C)
{
    int idx = blockIdx.x*blockDim.x + threadIdx.x;   // T*C
    if (idx >= T_TOK*C) return;
    int c = idx % C; int t = idx / C;
    int s = t & (SEQ-1); int b = t >> 8;
    float a = bias[c];
    int j0 = (s >= CK-1) ? s-(CK-1) : 0;
    for (int j = j0; j <= s; ++j){
        int k = j - s + (CK-1);
        a += in[(size_t)(b*SEQ+j)*istride + c] * w[c*CK + k];
    }
    out[idx] = a * sigf(a);
}

// ---------------- headwise 4x4 projection: q and k fused (xc read once) ----------
__global__ void headwise_qk_kernel(const float* __restrict__ xc,
                                   const float* __restrict__ Wq, const float* __restrict__ Wk,
                                   float* __restrict__ qout, float* __restrict__ kout)
{
    int idx = blockIdx.x*blockDim.x + threadIdx.x;   // T*256
    if (idx >= T_TOK*INNER) return;
    int c = idx & 255; int t = idx >> 8;
    int n = c >> 2, l = c & 3;
    const float* xr = xc + (size_t)t*256 + n*4;
    float x0 = xr[0], x1 = xr[1], x2 = xr[2], x3 = xr[3];
    const float* wq = Wq + n*16 + l;
    const float* wk = Wk + n*16 + l;
    qout[idx] = x0*wq[0] + x1*wq[4] + x2*wq[8] + x3*wq[12];
    kout[idx] = x0*wk[0] + x1*wk[4] + x2*wk[8] + x3*wk[12];
}

__global__ void headwise_inplace_kernel(float* __restrict__ up, const float* __restrict__ W)
{
    int idx = blockIdx.x*blockDim.x + threadIdx.x;   // T*64
    if (idx >= T_TOK*64) return;
    int n = idx & 63; int t = idx >> 6;
    float* xr = up + (size_t)t*512 + n*4;
    float x0 = xr[0], x1 = xr[1], x2 = xr[2], x3 = xr[3];
    const float* w = W + n*16;
    for (int l = 0; l < 4; ++l)
        xr[l] = x0*w[l] + x1*w[4+l] + x2*w[8+l] + x3*w[12+l];
}

// ---------------- ig/fg projection: one WAVE per token ---------------------------
__global__ void __launch_bounds__(256)
gateproj_kernel(const float* __restrict__ q, const float* __restrict__ k,
                const float* __restrict__ up,
                const float* __restrict__ Wig, const float* __restrict__ big,
                const float* __restrict__ Wfg, const float* __restrict__ bfg,
                float* __restrict__ igt, float* __restrict__ fgt)
{
    int t = blockIdx.x*4 + (threadIdx.x >> 6);       // token; 4 waves/block
    int lane = threadIdx.x & 63;
    float4 si = make_float4(0.f,0.f,0.f,0.f);
    float4 sf = make_float4(0.f,0.f,0.f,0.f);
    #pragma unroll
    for (int c = 0; c < 12; ++c){
        int j = c*64 + lane;
        float xv;
        if (c < 4)      xv = q[(size_t)t*256 + j];
        else if (c < 8) xv = k[(size_t)t*256 + j - 256];
        else            xv = up[(size_t)t*512 + j - 512];   // v in up[:, :256]
        float4 wi = *(const float4*)(Wig + (size_t)j*4);
        float4 wf = *(const float4*)(Wfg + (size_t)j*4);
        si.x = fmaf(xv, wi.x, si.x); si.y = fmaf(xv, wi.y, si.y);
        si.z = fmaf(xv, wi.z, si.z); si.w = fmaf(xv, wi.w, si.w);
        sf.x = fmaf(xv, wf.x, sf.x); sf.y = fmaf(xv, wf.y, sf.y);
        sf.z = fmaf(xv, wf.z, sf.z); sf.w = fmaf(xv, wf.w, sf.w);
    }
    #pragma unroll
    for (int off = 32; off >= 1; off >>= 1){
        si.x += __shfl_xor(si.x, off); si.y += __shfl_xor(si.y, off);
        si.z += __shfl_xor(si.z, off); si.w += __shfl_xor(si.w, off);
        sf.x += __shfl_xor(sf.x, off); sf.y += __shfl_xor(sf.y, off);
        sf.z += __shfl_xor(sf.z, off); sf.w += __shfl_xor(sf.w, off);
    }
    int b = t >> 8, s = t & 255;
    int hh = lane & 3;
    float vi = (hh==0) ? si.x : (hh==1) ? si.y : (hh==2) ? si.z : si.w;
    float vf = (hh==0) ? sf.x : (hh==1) ? sf.y : (hh==2) ? sf.z : sf.w;
    if (lane < 4)       igt[(b*4+hh)*SEQ + s] = vi + big[hh];
    else if (lane < 8)  fgt[(b*4+hh)*SEQ + s] = vf + bfg[hh];
}

// ---------------- cs: one WAVE per (b,h), parallel logsigmoid + wave scan --------
__global__ void __launch_bounds__(64)
cs_kernel(const float* __restrict__ fgt, const float* __restrict__ igt,
          float* __restrict__ cs, float* __restrict__ pm)
{
    int bh = blockIdx.x;                             // 256 blocks
    int lane = threadIdx.x;                          // 64
    float4 f4 = *(const float4*)(fgt + (size_t)bh*SEQ + lane*4);
    float4 i4 = *(const float4*)(igt + (size_t)bh*SEQ + lane*4);
    float lf0, lf1, lf2, lf3;
    { float f = f4.x; lf0 = (f > 0.f) ? -log1pf(__expf(-f)) : f - log1pf(__expf(f)); }
    { float f = f4.y; lf1 = (f > 0.f) ? -log1pf(__expf(-f)) : f - log1pf(__expf(f)); }
    { float f = f4.z; lf2 = (f > 0.f) ? -log1pf(__expf(-f)) : f - log1pf(__expf(f)); }
    { float f = f4.w; lf3 = (f > 0.f) ? -log1pf(__expf(-f)) : f - log1pf(__expf(f)); }
    float p0 = lf0, p1 = p0 + lf1, p2 = p1 + lf2, p3 = p2 + lf3;
    float incl = p3;
    #pragma unroll
    for (int off = 1; off < 64; off <<= 1){
        float v = __shfl_up(incl, off);
        if (lane >= off) incl += v;
    }
    float excl = __shfl_up(incl, 1);
    if (lane == 0) excl = 0.f;
    float c0 = excl + p0, c1 = excl + p1, c2 = excl + p2, c3 = excl + p3;
    *(float4*)(cs + (size_t)bh*SEQ + lane*4) = make_float4(c0, c1, c2, c3);
    float u0 = i4.x - c0, u1 = i4.y - c1, u2 = i4.z - c2, u3 = i4.w - c3;
    float m0 = u0, m1 = fmaxf(m0, u1), m2 = fmaxf(m1, u2), m3 = fmaxf(m2, u3);
    float inm = m3;
    #pragma unroll
    for (int off = 1; off < 64; off <<= 1){
        float v = __shfl_up(inm, off);
        if (lane >= off) inm = fmaxf(inm, v);
    }
    float exm = __shfl_up(inm, 1);
    if (lane == 0) exm = -1e30f;
    *(float4*)(pm + (size_t)bh*SEQ + lane*4) =
        make_float4(fmaxf(exm, m0), fmaxf(exm, m1), fmaxf(exm, m2), fmaxf(exm, m3));
}

// ---------------- attention v8: balanced tile-pairing ----------------------------
// Round-9 counters: Occupancy 12.5% time-avg = tail of qt=3 blocks running 1/CU
// (grid == max residency; short blocks free slots with nothing to schedule).
// Fix: block = (bh, pair); runs TWO sequential passes over tiles {3-pair, pair}
// -> every block does exactly 5 chunk-units; grid 512, 2 blocks/CU, uniform
// finish. Per-pass body identical to round-7 (~128 VGPR live set; sequential
// passes, NOT concurrent 2-row residency which spilled in round 8).
#define AC 32
#define QB 64
__global__ void __launch_bounds__(256)
attn_kernel(float* __restrict__ q, const float* __restrict__ kk,
            const float* __restrict__ up,
            const float* __restrict__ igt, const float* __restrict__ cs,
            const float* __restrict__ pm)
{
    __shared__ float k_sh[AC][DHM];      // 8 KB
    __shared__ float v_sh[AC][DHM];      // 8 KB
    __shared__ float S_sh[QB][33];       // 8.4 KB
    __shared__ float u_sh[SEQ];          // 1 KB
    int blk = blockIdx.x;                // bh*2 + pair
    int bh = blk >> 1, pair = blk & 1;
    int b = bh >> 2, hh = bh & 3;
    int tid = threadIdx.x;
    int il = tid & 63;                   // local row
    int g = tid >> 6;                    // 0..3: phase1 j-eighth; phase2 d-quarter
    u_sh[tid] = igt[bh*SEQ + tid] - cs[bh*SEQ + tid];

    for (int pass = 0; pass < 2; ++pass){
        int qt = pass ? pair : (3 - pair);
        int i = qt*QB + il;              // global row
        float csi = cs[bh*SEQ + i];
        float m   = csi + pm[bh*SEQ + i];
        const float4* qp4 = (const float4*)(q + ((size_t)(b*SEQ + i)*INNER + hh*DHM));
        float4 qr4[16];
        #pragma unroll
        for (int r = 0; r < 16; ++r) qr4[r] = qp4[r];
        float4 acc4[4];
        #pragma unroll
        for (int r = 0; r < 4; ++r) acc4[r] = make_float4(0.f,0.f,0.f,0.f);
        float ssum = 0.f;
        int cend = (qt+1)*QB;

        for (int c0 = 0; c0 < cend; c0 += AC){
            // stage K/V chunk: 256 threads cover 2*32*16 float4 (4 each)
            {
                int half = tid >> 7;         // 0: K  1: V
                int idx2 = tid & 127;
                int r0 = idx2 >> 4;          // 0..7
                int d4 = idx2 & 15;
                #pragma unroll
                for (int rr = 0; rr < 4; ++rr){
                    int r = r0 + rr*8;
                    size_t tj = (size_t)(b*SEQ + c0 + r);
                    if (half == 0)
                        ((float4*)&k_sh[r][0])[d4] = *(const float4*)(kk + tj*INNER + hh*DHM + d4*4);
                    else
                        ((float4*)&v_sh[r][0])[d4] = *(const float4*)(up + tj*512 + hh*DHM + d4*4);
                }
            }
            __syncthreads();
            if (i >= c0){
                // phase1: 8 dots, masked, scaled, exp'd -> S_sh[il][g*8 + jj]
                #pragma unroll
                for (int jj = 0; jj < 8; ++jj){
                    int jl = g*8 + jj;
                    const float4* kr = (const float4*)&k_sh[jl][0];
                    float d0=0.f, d1=0.f, d2=0.f, d3=0.f;
                    #pragma unroll
                    for (int r4 = 0; r4 < 4; ++r4){
                        float4 ka = kr[r4*4+0], kb2 = kr[r4*4+1];
                        float4 kc = kr[r4*4+2], kd  = kr[r4*4+3];
                        float4 qa = qr4[r4*4+0], qb2 = qr4[r4*4+1];
                        float4 qc = qr4[r4*4+2], qd  = qr4[r4*4+3];
                        d0 += qa.x*ka.x + qa.y*ka.y + qa.z*ka.z + qa.w*ka.w;
                        d1 += qb2.x*kb2.x + qb2.y*kb2.y + qb2.z*kb2.z + qb2.w*kb2.w;
                        d2 += qc.x*kc.x + qc.y*kc.y + qc.z*kc.z + qc.w*kc.w;
                        d3 += qd.x*kd.x + qd.y*kd.y + qd.z*kd.z + qd.w*kd.w;
                    }
                    float dot = (d0+d1) + (d2+d3);
                    int jg = c0 + jl;
                    float arg = fminf(csi + u_sh[jg] - m, 0.f);
                    S_sh[il][jl] = (jg <= i) ? dot * 0.125f * __expf(arg) : 0.f;
                }
            }
            __syncthreads();
            if (i >= c0){
                // phase2: accumulate 16 output dims over the chunk's 32 j's
                #pragma unroll
                for (int jj = 0; jj < AC; ++jj){
                    float sv = S_sh[il][jj];
                    ssum += sv;
                    const float4* vr = (const float4*)&v_sh[jj][g*16];
                    #pragma unroll
                    for (int r = 0; r < 4; ++r){
                        float4 vv = vr[r];
                        acc4[r].x += sv*vv.x; acc4[r].y += sv*vv.y;
                        acc4[r].z += sv*vv.z; acc4[r].w += sv*vv.w;
                    }
                }
            }
            __syncthreads();
        }
        float nrm = fmaxf(fabsf(ssum), __expf(-m)) + 1e-6f;
        float rn = 1.f/nrm;
        float4* op = (float4*)(q + ((size_t)(b*SEQ + i)*INNER + hh*DHM + g*16));
        #pragma unroll
        for (int r = 0; r < 4; ++r){
            float4 o = acc4[r];
            o.x *= rn; o.y *= rn; o.z *= rn; o.w *= rn;
            op[r] = o;
        }
        // last loop barrier already covers LDS reads; pass-1 Q rows are disjoint
        // from pass-0 output rows, so no extra sync needed.
    }
}

// ---------------- mh_gate: one WAVE per (t,h), coalesced -------------------------
__global__ void __launch_bounds__(256)
mh_gate_kernel(float* __restrict__ q, const float* __restrict__ up,
               const float* __restrict__ xc,
               const float* __restrict__ gnw, const float* __restrict__ skip)
{
    int unit = blockIdx.x*4 + (threadIdx.x >> 6);    // t*4 + hh
    int lane = threadIdx.x & 63;
    int t = unit >> 2, hh = unit & 3;
    int c = hh*DHM + lane;
    float v = q[(size_t)t*256 + c];
    float s = v, ss = v*v;
    #pragma unroll
    for (int off = 32; off >= 1; off >>= 1){ s += __shfl_xor(s,off); ss += __shfl_xor(ss,off); }
    float mu  = s * (1.f/64.f);
    float var = fmaxf(ss * (1.f/64.f) - mu*mu, 0.f);
    float r   = rsqrtf(var + 1e-6f);
    float hn  = (v-mu)*r*gnw[c];
    float z   = up[(size_t)t*512 + 256 + c];
    q[(size_t)t*256 + c] = (hn + skip[c]*xc[(size_t)t*256 + c]) * (z*sigf(z));
}

// ---------------- sLSTM gates: weight-stationary registers -----------------------
#define SG_TOK 16
__global__ void __launch_bounds__(512)
slstm_gates_kernel(const float* __restrict__ xc, const float* __restrict__ xl,
                   const float* __restrict__ Wg, const float* __restrict__ bg,
                   float* __restrict__ gates)
{
    int tid = threadIdx.x;
    int l  = tid & 31;
    int gn = tid >> 5;            // g*4+n
    int g  = gn >> 2, n = gn & 3;
    int t0 = blockIdx.x * SG_TOK;
    float wr[32];
    #pragma unroll
    for (int k = 0; k < 32; ++k) wr[k] = Wg[(size_t)gn*1024 + k*32 + l];
    float bias = bg[g*128 + n*32 + l];
    const float* xin = (g < 2) ? xc : xl;
    #pragma unroll 4
    for (int t = 0; t < SG_TOK; ++t){
        int tok = t0 + t;
        const float4* xr = (const float4*)(xin + (size_t)tok*128 + n*32);
        float a = bias;
        #pragma unroll
        for (int k4 = 0; k4 < 8; ++k4){
            float4 xv = xr[k4];
            a = fmaf(xv.x, wr[k4*4+0], a);
            a = fmaf(xv.y, wr[k4*4+1], a);
            a = fmaf(xv.z, wr[k4*4+2], a);
            a = fmaf(xv.w, wr[k4*4+3], a);
        }
        int b = tok >> 8, s = tok & 255;
        gates[(size_t)((b*4+n)*SEQ + s)*128 + l*4 + g] = a;
    }
}

// ---------------- sLSTM recurrence: shortened critical path ----------------------
__global__ void __launch_bounds__(64)
slstm_scan_kernel(const float* __restrict__ gates, const float* __restrict__ Rw,
                  float* __restrict__ ys)
{
    int bn = blockIdx.x;                 // b*4 + n
    int b = bn >> 2, n = bn & 3;
    int lane = threadIdx.x;              // 0..63
    int l = lane & 31;
    int hi = lane >> 5;                  // 0: gates i,f   1: gates z,o
    int gA = hi ? 2 : 0, gB = hi ? 3 : 1;
    const float* Rbase = Rw + (size_t)n*1024 + l;
    float Ra[32], Rb[32];
    #pragma unroll
    for (int k = 0; k < 32; ++k){
        Ra[k] = Rbase[(size_t)gA*4096 + k*32];
        Rb[k] = Rbase[(size_t)gB*4096 + k*32];
    }
    const float* gbase = gates + (size_t)bn*SEQ*128 + l*4 + (hi ? 2 : 0);
    float* yrow = ys + (size_t)b*SEQ*128 + n*32 + l;
    float2 g0 = *(const float2*)(gbase);
    float2 g1 = *(const float2*)(gbase + 128);
    float c = 0.f, nst = 0.f, m = 0.f, hst = 0.f;
    for (int s = 0; s < SEQ; ++s){
        float2 g2 = (s+2 < SEQ) ? *(const float2*)(gbase + (size_t)(s+2)*128)
                                : make_float2(0.f, 0.f);
        float ra0=0.f, ra1=0.f, ra2=0.f, ra3=0.f;
        float rb0=0.f, rb1=0.f, rb2=0.f, rb3=0.f;
        #pragma unroll
        for (int k = 0; k < 8; ++k){
            float h0 = bcast_lane(hst, k);
            float h1 = bcast_lane(hst, k+8);
            float h2 = bcast_lane(hst, k+16);
            float h3 = bcast_lane(hst, k+24);
            ra0 = fmaf(h0, Ra[k],    ra0); rb0 = fmaf(h0, Rb[k],    rb0);
            ra1 = fmaf(h1, Ra[k+8],  ra1); rb1 = fmaf(h1, Rb[k+8],  rb1);
            ra2 = fmaf(h2, Ra[k+16], ra2); rb2 = fmaf(h2, Rb[k+16], rb2);
            ra3 = fmaf(h3, Ra[k+24], ra3); rb3 = fmaf(h3, Rb[k+24], rb3);
        }
        float ra = (ra0+ra1) + (ra2+ra3);
        float rb = (rb0+rb1) + (rb2+rb3);
        float pa = g0.x + ra;            // lo: ir   hi: zr
        float pb = g0.y + rb;            // lo: fr   hi: orr
        float zr  = __shfl_xor(pa, 32);
        float orr = __shfl_xor(pb, 32);
        float mnew = fmaxf(pb + m, pa);
        float iv = __expf(pa - mnew);
        float fv = __expf(pb + m - mnew);
        float zt = 1.f - 2.f*frcp(1.f + __expf(2.f*zr));
        float ov = frcp(1.f + __expf(-orr));
        c   = fv*c + iv*zt;
        nst = fv*nst + iv;
        hst = ov * c * frcp(nst + 1e-8f);
        m = mnew;
        if (!hi) yrow[(size_t)s*128] = hst;
        g0 = g1; g1 = g2;
    }
}

// ---------------- mh_add: 32-lane group per (t,n), coalesced ---------------------
__global__ void __launch_bounds__(256)
mh_add_kernel(const float* __restrict__ ys, const float* __restrict__ gnw,
              float* __restrict__ h)
{
    int unit = blockIdx.x*8 + (threadIdx.x >> 5);    // t*4 + n
    int l = threadIdx.x & 31;
    int t = unit >> 2, n = unit & 3;
    float v = ys[(size_t)t*128 + n*32 + l];
    float s = v, ss = v*v;
    #pragma unroll
    for (int off = 16; off >= 1; off >>= 1){ s += __shfl_xor(s,off); ss += __shfl_xor(ss,off); }
    float mu  = s * (1.f/32.f);
    float var = fmaxf(ss * (1.f/32.f) - mu*mu, 0.f);
    float r   = rsqrtf(var + 1e-6f);
    h[(size_t)t*128 + n*32 + l] += (v-mu)*r*gnw[n*32+l];
}

__global__ void geluv_kernel(const float* __restrict__ up, float* __restrict__ out)
{
    int idx = blockIdx.x*blockDim.x + threadIdx.x;   // T*192
    if (idx >= T_TOK*FF) return;
    int j = idx % FF; int t = idx / FF;
    float g  = up[(size_t)t*384 + j];
    float vv = up[(size_t)t*384 + FF + j];
    float gel = 0.5f*g*(1.f + tanhf(0.7978845608028654f*(g + 0.044715f*g*g*g)));
    out[idx] = gel*vv;
}

// ---------------- final projection: fp32 output ----------------
__global__ void out_kernel(const float* __restrict__ ln, const float* __restrict__ W,
                           const float* __restrict__ bias, float* __restrict__ out)
{
    int idx = threadIdx.x;                           // 192 threads, 1 block
    if (idx >= BATCH*3) return;
    int b = idx / 3, e = idx % 3;
    float s = bias[e];
    const float* xr = ln + ((size_t)(b*SEQ + SEQ-1))*128;
    for (int d = 0; d < 128; ++d) s += xr[d]*W[d*3+e];
    out[idx] = s;
}

#define LCHK do { \
    if (hipGetLastError() != hipSuccess){ \
        sentinel_kernel<<<1, 192, 0, stream>>>((float*)d_out, 3000.0f + 32.0f*(float)launch_idx); \
        return; } \
    ++launch_idx; } while(0)

extern "C" void kernel_launch(void* const* d_in, const int* in_sizes, int n_in,
                              void* d_out, int out_size, void* d_ws, size_t ws_size,
                              hipStream_t stream)
{
    (void)out_size;
    static const int expected_sizes[30] = {
        49152, 384, 128, 512, 262144, 4096, 1024, 4096, 4096, 4096,
        12288, 16, 12288, 16, 1024, 1024, 131072, 256, 1024, 256,
        32768, 1024, 32768, 256, 256, 98304, 49152, 128, 384, 3
    };
    if (n_in != 30){ sentinel_kernel<<<1,192,0,stream>>>((float*)d_out, 5000.0f); return; }
    for (int i = 0; i < 30; ++i)
        if (in_sizes[i] != expected_sizes[i]){
            sentinel_kernel<<<1,192,0,stream>>>((float*)d_out, 2000.0f + 32.0f*i); return; }
    if (ws_size < (size_t)96*1024*1024){
        sentinel_kernel<<<1,192,0,stream>>>((float*)d_out, 1000.0f + (float)(ws_size >> 20)); return; }

    const float* x        = (const float*)d_in[0];
    const float* W_emb    = (const float*)d_in[1];
    const float* b_emb    = (const float*)d_in[2];
    const float* m_ln_w   = (const float*)d_in[3];
    const float* m_Wup    = (const float*)d_in[4];
    const float* m_conv_w = (const float*)d_in[5];
    const float* m_conv_b = (const float*)d_in[6];
    const float* m_Wq     = (const float*)d_in[7];
    const float* m_Wk     = (const float*)d_in[8];
    const float* m_Wv     = (const float*)d_in[9];
    const float* m_Wig    = (const float*)d_in[10];
    const float* m_big    = (const float*)d_in[11];
    const float* m_Wfg    = (const float*)d_in[12];
    const float* m_bfg    = (const float*)d_in[13];
    const float* m_gn_w   = (const float*)d_in[14];
    const float* m_skip   = (const float*)d_in[15];
    const float* m_Wdown  = (const float*)d_in[16];
    const float* s_ln_w   = (const float*)d_in[17];
    const float* s_conv_w = (const float*)d_in[18];
    const float* s_conv_b = (const float*)d_in[19];
    const float* s_Wg     = (const float*)d_in[20];
    const float* s_bg     = (const float*)d_in[21];
    const float* s_R      = (const float*)d_in[22];
    const float* s_gn_w   = (const float*)d_in[23];
    const float* s_ln2_w  = (const float*)d_in[24];
    const float* s_Wff_up = (const float*)d_in[25];
    const float* s_Wff_dn = (const float*)d_in[26];
    const float* post_ln  = (const float*)d_in[27];
    const float* W_out    = (const float*)d_in[28];
    const float* b_out    = (const float*)d_in[29];

    float* ws  = (float*)d_ws;
    float* h   = ws;                         // T*128
    float* ln  = h   + (size_t)T_TOK*128;    // T*128; igt/fgt/cs/pm alias (ln dead then)
    float* up  = ln  + (size_t)T_TOK*128;    // T*512
    float* xc  = up  + (size_t)T_TOK*512;    // T*256
    float* qb  = xc  + (size_t)T_TOK*256;    // T*256
    float* kb  = qb  + (size_t)T_TOK*256;    // T*256 (k; sLSTM ys)
    float* igt  = ln;
    float* fgt  = ln + 65536;
    float* csb  = ln + 2*65536;
    float* pmb  = ln + 3*65536;

    int launch_idx = 0;
    (void)hipGetLastError();

    embed_kernel<<<(T_TOK*128)/256, 256, 0, stream>>>(x, W_emb, b_emb, h); LCHK;

    const char* bt = "msmsmm";
    int mi = 0, si = 0;
    for (int blk = 0; blk < 6; ++blk){
        if (bt[blk] == 'm'){
            ln_kernel<<<T_TOK, 64, 0, stream>>>(h, m_ln_w + mi*128, ln); LCHK;
            gemm_tiled_m128_kernel<<<(T_TOK/HM)*(512/HN), 256, 0, stream>>>(ln, m_Wup + (size_t)mi*65536, up, T_TOK, 512, 128, 0); LCHK;
            conv_silu_kernel<<<(T_TOK*256)/256, 256, 0, stream>>>(up, 512, m_conv_w + mi*1024, m_conv_b + mi*256, xc, 256); LCHK;
            headwise_qk_kernel<<<(T_TOK*256)/256, 256, 0, stream>>>(xc, m_Wq + mi*1024, m_Wk + mi*1024, qb, kb); LCHK;
            headwise_inplace_kernel<<<(T_TOK*64)/256, 256, 0, stream>>>(up, m_Wv + mi*1024); LCHK;
            gateproj_kernel<<<T_TOK/4, 256, 0, stream>>>(qb, kb, up, m_Wig + mi*3072, m_big + mi*4,
                                                         m_Wfg + mi*3072, m_bfg + mi*4, igt, fgt); LCHK;
            cs_kernel<<<BATCH*NH, 64, 0, stream>>>(fgt, igt, csb, pmb); LCHK;
            attn_kernel<<<BATCH*NH*2, 256, 0, stream>>>(qb, kb, up, igt, csb, pmb); LCHK;
            mh_gate_kernel<<<T_TOK, 256, 0, stream>>>(qb, up, xc, m_gn_w + mi*256, m_skip + mi*256); LCHK;
            gemm_tiled_kernel<<<(T_TOK/TM)*(128/TN), 256, 0, stream>>>(qb, m_Wdown + (size_t)mi*32768, h, T_TOK, 128, 256, 1); LCHK;
            ++mi;
        } else {
            ln_kernel<<<T_TOK, 64, 0, stream>>>(h, s_ln_w + si*128, ln); LCHK;
            conv_silu_kernel<<<(T_TOK*128)/256, 256, 0, stream>>>(ln, 128, s_conv_w + si*512, s_conv_b + si*128, xc, 128); LCHK;
            slstm_gates_kernel<<<T_TOK/SG_TOK, 512, 0, stream>>>(xc, ln, s_Wg + si*16384, s_bg + si*512, up); LCHK;
            slstm_scan_kernel<<<BATCH*4, 64, 0, stream>>>(up, s_R + si*16384, kb); LCHK;
            mh_add_kernel<<<T_TOK/2, 256, 0, stream>>>(kb, s_gn_w + si*128, h); LCHK;
            ln_kernel<<<T_TOK, 64, 0, stream>>>(h, s_ln2_w + si*128, ln); LCHK;
            gemm_tiled_m128_kernel<<<(T_TOK/HM)*(384/HN), 256, 0, stream>>>(ln, s_Wff_up + (size_t)si*49152, up, T_TOK, 384, 128, 0); LCHK;
            geluv_kernel<<<(T_TOK*192)/256, 256, 0, stream>>>(up, qb); LCHK;
            gemm_tiled_kernel<<<(T_TOK/TM)*(128/TN), 256, 0, stream>>>(qb, s_Wff_dn + (size_t)si*24576, h, T_TOK, 128, 192, 1); LCHK;
            ++si;
        }
    }

    ln_kernel<<<T_TOK, 64, 0, stream>>>(h, post_ln, ln); LCHK;
    out_kernel<<<1, 192, 0, stream>>>(ln, W_out, b_out, (float*)d_out); LCHK;
}

// Round 11
// 1531.454 us; speedup vs baseline: 1.9832x; 1.0247x over previous
//
#include <hip/hip_runtime.h>
#include <hip/hip_bf16.h>

#define D_MODEL 128
#define INNER 256
#define NH 4
#define DHM 64
#define SNH 4
#define SDH 32
#define FF 192
#define CK 4
#define BATCH 64
#define SEQ 256
#define T_TOK (BATCH*SEQ)   /* 16384 tokens */

typedef __hip_bfloat16 bf16;

__device__ __forceinline__ float sigf(float x){ return 1.0f/(1.0f+__expf(-x)); }
__device__ __forceinline__ float bcast_lane(float v, int k){
    return __uint_as_float(__builtin_amdgcn_readlane(__float_as_uint(v), k));
}
__device__ __forceinline__ float frcp(float x){ return __builtin_amdgcn_rcpf(x); }

// ---------------- sentinel writer (fp32) ----------------
__global__ void sentinel_kernel(float* __restrict__ out, float v)
{
    int idx = threadIdx.x;
    if (idx < BATCH*3) out[idx] = v;
}

// ---------------- embed ----------------
__global__ void embed_kernel(const float* __restrict__ x, const float* __restrict__ W,
                             const float* __restrict__ bias, float* __restrict__ h)
{
    int idx = blockIdx.x*blockDim.x + threadIdx.x;   // T*128
    if (idx >= T_TOK*D_MODEL) return;
    int d = idx & 127; int t = idx >> 7;
    float s = bias[d];
    #pragma unroll
    for (int i = 0; i < 3; ++i) s += x[t*3+i] * W[i*D_MODEL+d];
    h[idx] = s;
}

// ---------------- LN: one WAVE (64 threads) per token, coalesced ----------------
__global__ void ln_kernel(const float* __restrict__ x, const float* __restrict__ w,
                          float* __restrict__ out)
{
    int t = blockIdx.x; int lane = threadIdx.x;      // 64 threads
    float v0 = x[(size_t)t*128 + lane], v1 = x[(size_t)t*128 + 64 + lane];
    float s = v0 + v1, ss = v0*v0 + v1*v1;
    #pragma unroll
    for (int off = 32; off >= 1; off >>= 1){ s += __shfl_xor(s,off); ss += __shfl_xor(ss,off); }
    float mu  = s * (1.f/128.f);
    float var = fmaxf(ss * (1.f/128.f) - mu*mu, 0.f);
    float r   = rsqrtf(var + 1e-6f);
    out[(size_t)t*128 + lane]      = (v0-mu)*r*w[lane];
    out[(size_t)t*128 + 64 + lane] = (v1-mu)*r*w[64+lane];
}

// ---------------- tiled GEMM 64x64: C[M,N] (+)= A[M,K] * W[K,N] ----------------
#define TM 64
#define TN 64
#define TK 32
__global__ void __launch_bounds__(256)
gemm_tiled_kernel(const float* __restrict__ A, const float* __restrict__ W,
                  float* __restrict__ C, int M, int N, int Kd, int acc)
{
    int ntiles = N / TN;
    int bx = blockIdx.x % ntiles;
    int by = blockIdx.x / ntiles;
    __shared__ float As[TK][TM+1];   // +1 pad: kills 32-way write conflicts
    __shared__ float Ws[TK][TN];
    int tid = threadIdx.x;
    int tn = (tid & 15) * 4;         // col within tile
    int tm = (tid >> 4) * 4;         // row within tile
    float accr[4][4] = {{0.f}};
    for (int k0 = 0; k0 < Kd; k0 += TK){
        #pragma unroll
        for (int i = tid; i < TM*TK; i += 256){
            int c2 = i & 31, r = i >> 5;             // k fastest -> coalesced global
            As[c2][r] = A[(size_t)(by*TM + r)*Kd + k0 + c2];
        }
        #pragma unroll
        for (int i = tid; i < TK*TN; i += 256){
            int c2 = i & 63, r = i >> 6;             // n fastest -> coalesced global
            Ws[r][c2] = W[(size_t)(k0 + r)*N + bx*TN + c2];
        }
        __syncthreads();
        #pragma unroll
        for (int k = 0; k < TK; ++k){
            float a0 = As[k][tm], a1 = As[k][tm+1], a2 = As[k][tm+2], a3 = As[k][tm+3];
            float4 wv = *(const float4*)&Ws[k][tn];
            accr[0][0] = fmaf(a0, wv.x, accr[0][0]); accr[0][1] = fmaf(a0, wv.y, accr[0][1]);
            accr[0][2] = fmaf(a0, wv.z, accr[0][2]); accr[0][3] = fmaf(a0, wv.w, accr[0][3]);
            accr[1][0] = fmaf(a1, wv.x, accr[1][0]); accr[1][1] = fmaf(a1, wv.y, accr[1][1]);
            accr[1][2] = fmaf(a1, wv.z, accr[1][2]); accr[1][3] = fmaf(a1, wv.w, accr[1][3]);
            accr[2][0] = fmaf(a2, wv.x, accr[2][0]); accr[2][1] = fmaf(a2, wv.y, accr[2][1]);
            accr[2][2] = fmaf(a2, wv.z, accr[2][2]); accr[2][3] = fmaf(a2, wv.w, accr[2][3]);
            accr[3][0] = fmaf(a3, wv.x, accr[3][0]); accr[3][1] = fmaf(a3, wv.y, accr[3][1]);
            accr[3][2] = fmaf(a3, wv.z, accr[3][2]); accr[3][3] = fmaf(a3, wv.w, accr[3][3]);
        }
        __syncthreads();
    }
    #pragma unroll
    for (int i = 0; i < 4; ++i){
        size_t off = (size_t)(by*TM + tm + i)*N + bx*TN + tn;
        if (acc){
            float4 old = *(float4*)&C[off];
            old.x += accr[i][0]; old.y += accr[i][1];
            old.z += accr[i][2]; old.w += accr[i][3];
            *(float4*)&C[off] = old;
        } else {
            *(float4*)&C[off] = make_float4(accr[i][0], accr[i][1], accr[i][2], accr[i][3]);
        }
    }
}

// ---------------- tiled GEMM 128x64: 8x4 outputs/thread, for N>=384 K=128 --------
#define HM 128
#define HN 64
#define HK 32
__global__ void __launch_bounds__(256)
gemm_tiled_m128_kernel(const float* __restrict__ A, const float* __restrict__ W,
                       float* __restrict__ C, int M, int N, int Kd, int acc)
{
    int ntiles = N / HN;
    int bx = blockIdx.x % ntiles;
    int by = blockIdx.x / ntiles;
    __shared__ float As[HK][HM+4];   // stride 132: float4-aligned rows
    __shared__ float Ws[HK][HN];
    int tid = threadIdx.x;
    int tn = (tid & 15) * 4;         // col within tile
    int tm = (tid >> 4) * 8;         // row within tile
    float accr[8][4] = {{0.f}};
    for (int k0 = 0; k0 < Kd; k0 += HK){
        #pragma unroll
        for (int i = tid; i < HM*HK; i += 256){
            int c2 = i & 31, r = i >> 5;             // k fastest -> coalesced global
            As[c2][r] = A[(size_t)(by*HM + r)*Kd + k0 + c2];
        }
        #pragma unroll
        for (int i = tid; i < HK*HN; i += 256){
            int c2 = i & 63, r = i >> 6;             // n fastest -> coalesced global
            Ws[r][c2] = W[(size_t)(k0 + r)*N + bx*HN + c2];
        }
        __syncthreads();
        #pragma unroll
        for (int k = 0; k < HK; ++k){
            float4 a0 = *(const float4*)&As[k][tm];
            float4 a1 = *(const float4*)&As[k][tm+4];
            float4 wv = *(const float4*)&Ws[k][tn];
            float av[8] = {a0.x,a0.y,a0.z,a0.w,a1.x,a1.y,a1.z,a1.w};
            #pragma unroll
            for (int ii = 0; ii < 8; ++ii){
                accr[ii][0] = fmaf(av[ii], wv.x, accr[ii][0]);
                accr[ii][1] = fmaf(av[ii], wv.y, accr[ii][1]);
                accr[ii][2] = fmaf(av[ii], wv.z, accr[ii][2]);
                accr[ii][3] = fmaf(av[ii], wv.w, accr[ii][3]);
            }
        }
        __syncthreads();
    }
    #pragma unroll
    for (int i = 0; i < 8; ++i){
        size_t off = (size_t)(by*HM + tm + i)*N + bx*HN + tn;
        if (acc){
            float4 old = *(float4*)&C[off];
            old.x += accr[i][0]; old.y += accr[i][1];
            old.z += accr[i][2]; old.w += accr[i][3];
            *(float4*)&C[off] = old;
        } else {
            *(float4*)&C[off] = make_float4(accr[i][0], accr[i][1], accr[i][2], accr[i][3]);
        }
    }
}

// ---------------- causal conv (K=4) + silu ----------------
__global__ void conv_silu_kernel(const float* __restrict__ in, int istride,
                                 const float* __restrict__ w, const float* __restrict__ bias,
                                 float* __restrict__ out, int C)
{
    int idx = blockIdx.x*blockDim.x + threadIdx.x;   // T*C
    if (idx >= T_TOK*C) return;
    int c = idx % C; int t = idx / C;
    int s = t & (SEQ-1); int b = t >> 8;
    float a = bias[c];
    int j0 = (s >= CK-1) ? s-(CK-1) : 0;
    for (int j = j0; j <= s; ++j){
        int k = j - s + (CK-1);
        a += in[(size_t)(b*SEQ+j)*istride + c] * w[c*CK + k];
    }
    out[idx] = a * sigf(a);
}

// ---------------- headwise 4x4 projection: q and k fused (xc read once) ----------
__global__ void headwise_qk_kernel(const float* __restrict__ xc,
                                   const float* __restrict__ Wq, const float* __restrict__ Wk,
                                   float* __restrict__ qout, float* __restrict__ kout)
{
    int idx = blockIdx.x*blockDim.x + threadIdx.x;   // T*256
    if (idx >= T_TOK*INNER) return;
    int c = idx & 255; int t = idx >> 8;
    int n = c >> 2, l = c & 3;
    const float* xr = xc + (size_t)t*256 + n*4;
    float x0 = xr[0], x1 = xr[1], x2 = xr[2], x3 = xr[3];
    const float* wq = Wq + n*16 + l;
    const float* wk = Wk + n*16 + l;
    qout[idx] = x0*wq[0] + x1*wq[4] + x2*wq[8] + x3*wq[12];
    kout[idx] = x0*wk[0] + x1*wk[4] + x2*wk[8] + x3*wk[12];
}

__global__ void headwise_inplace_kernel(float* __restrict__ up, const float* __restrict__ W)
{
    int idx = blockIdx.x*blockDim.x + threadIdx.x;   // T*64
    if (idx >= T_TOK*64) return;
    int n = idx & 63; int t = idx >> 6;
    float* xr = up + (size_t)t*512 + n*4;
    float x0 = xr[0], x1 = xr[1], x2 = xr[2], x3 = xr[3];
    const float* w = W + n*16;
    for (int l = 0; l < 4; ++l)
        xr[l] = x0*w[l] + x1*w[4+l] + x2*w[8+l] + x3*w[12+l];
}

// ---------------- ig/fg projection: one WAVE per token ---------------------------
__global__ void __launch_bounds__(256)
gateproj_kernel(const float* __restrict__ q, const float* __restrict__ k,
                const float* __restrict__ up,
                const float* __restrict__ Wig, const float* __restrict__ big,
                const float* __restrict__ Wfg, const float* __restrict__ bfg,
                float* __restrict__ igt, float* __restrict__ fgt)
{
    int t = blockIdx.x*4 + (threadIdx.x >> 6);       // token; 4 waves/block
    int lane = threadIdx.x & 63;
    float4 si = make_float4(0.f,0.f,0.f,0.f);
    float4 sf = make_float4(0.f,0.f,0.f,0.f);
    #pragma unroll
    for (int c = 0; c < 12; ++c){
        int j = c*64 + lane;
        float xv;
        if (c < 4)      xv = q[(size_t)t*256 + j];
        else if (c < 8) xv = k[(size_t)t*256 + j - 256];
        else            xv = up[(size_t)t*512 + j - 512];   // v in up[:, :256]
        float4 wi = *(const float4*)(Wig + (size_t)j*4);
        float4 wf = *(const float4*)(Wfg + (size_t)j*4);
        si.x = fmaf(xv, wi.x, si.x); si.y = fmaf(xv, wi.y, si.y);
        si.z = fmaf(xv, wi.z, si.z); si.w = fmaf(xv, wi.w, si.w);
        sf.x = fmaf(xv, wf.x, sf.x); sf.y = fmaf(xv, wf.y, sf.y);
        sf.z = fmaf(xv, wf.z, sf.z); sf.w = fmaf(xv, wf.w, sf.w);
    }
    #pragma unroll
    for (int off = 32; off >= 1; off >>= 1){
        si.x += __shfl_xor(si.x, off); si.y += __shfl_xor(si.y, off);
        si.z += __shfl_xor(si.z, off); si.w += __shfl_xor(si.w, off);
        sf.x += __shfl_xor(sf.x, off); sf.y += __shfl_xor(sf.y, off);
        sf.z += __shfl_xor(sf.z, off); sf.w += __shfl_xor(sf.w, off);
    }
    int b = t >> 8, s = t & 255;
    int hh = lane & 3;
    float vi = (hh==0) ? si.x : (hh==1) ? si.y : (hh==2) ? si.z : si.w;
    float vf = (hh==0) ? sf.x : (hh==1) ? sf.y : (hh==2) ? sf.z : sf.w;
    if (lane < 4)       igt[(b*4+hh)*SEQ + s] = vi + big[hh];
    else if (lane < 8)  fgt[(b*4+hh)*SEQ + s] = vf + bfg[hh];
}

// ---------------- cs: one WAVE per (b,h), parallel logsigmoid + wave scan --------
__global__ void __launch_bounds__(64)
cs_kernel(const float* __restrict__ fgt, const float* __restrict__ igt,
          float* __restrict__ cs, float* __restrict__ pm)
{
    int bh = blockIdx.x;                             // 256 blocks
    int lane = threadIdx.x;                          // 64
    float4 f4 = *(const float4*)(fgt + (size_t)bh*SEQ + lane*4);
    float4 i4 = *(const float4*)(igt + (size_t)bh*SEQ + lane*4);
    float lf0, lf1, lf2, lf3;
    { float f = f4.x; lf0 = (f > 0.f) ? -log1pf(__expf(-f)) : f - log1pf(__expf(f)); }
    { float f = f4.y; lf1 = (f > 0.f) ? -log1pf(__expf(-f)) : f - log1pf(__expf(f)); }
    { float f = f4.z; lf2 = (f > 0.f) ? -log1pf(__expf(-f)) : f - log1pf(__expf(f)); }
    { float f = f4.w; lf3 = (f > 0.f) ? -log1pf(__expf(-f)) : f - log1pf(__expf(f)); }
    float p0 = lf0, p1 = p0 + lf1, p2 = p1 + lf2, p3 = p2 + lf3;
    float incl = p3;
    #pragma unroll
    for (int off = 1; off < 64; off <<= 1){
        float v = __shfl_up(incl, off);
        if (lane >= off) incl += v;
    }
    float excl = __shfl_up(incl, 1);
    if (lane == 0) excl = 0.f;
    float c0 = excl + p0, c1 = excl + p1, c2 = excl + p2, c3 = excl + p3;
    *(float4*)(cs + (size_t)bh*SEQ + lane*4) = make_float4(c0, c1, c2, c3);
    float u0 = i4.x - c0, u1 = i4.y - c1, u2 = i4.z - c2, u3 = i4.w - c3;
    float m0 = u0, m1 = fmaxf(m0, u1), m2 = fmaxf(m1, u2), m3 = fmaxf(m2, u3);
    float inm = m3;
    #pragma unroll
    for (int off = 1; off < 64; off <<= 1){
        float v = __shfl_up(inm, off);
        if (lane >= off) inm = fmaxf(inm, v);
    }
    float exm = __shfl_up(inm, 1);
    if (lane == 0) exm = -1e30f;
    *(float4*)(pm + (size_t)bh*SEQ + lane*4) =
        make_float4(fmaxf(exm, m0), fmaxf(exm, m1), fmaxf(exm, m2), fmaxf(exm, m3));
}

// ---------------- attention: balanced tile-pairing (round-10, measured <98us) ----
#define AC 32
#define QB 64
__global__ void __launch_bounds__(256)
attn_kernel(float* __restrict__ q, const float* __restrict__ kk,
            const float* __restrict__ up,
            const float* __restrict__ igt, const float* __restrict__ cs,
            const float* __restrict__ pm)
{
    __shared__ float k_sh[AC][DHM];      // 8 KB
    __shared__ float v_sh[AC][DHM];      // 8 KB
    __shared__ float S_sh[QB][33];       // 8.4 KB
    __shared__ float u_sh[SEQ];          // 1 KB
    int blk = blockIdx.x;                // bh*2 + pair
    int bh = blk >> 1, pair = blk & 1;
    int b = bh >> 2, hh = bh & 3;
    int tid = threadIdx.x;
    int il = tid & 63;                   // local row
    int g = tid >> 6;                    // 0..3: phase1 j-eighth; phase2 d-quarter
    u_sh[tid] = igt[bh*SEQ + tid] - cs[bh*SEQ + tid];

    for (int pass = 0; pass < 2; ++pass){
        int qt = pass ? pair : (3 - pair);
        int i = qt*QB + il;              // global row
        float csi = cs[bh*SEQ + i];
        float m   = csi + pm[bh*SEQ + i];
        const float4* qp4 = (const float4*)(q + ((size_t)(b*SEQ + i)*INNER + hh*DHM));
        float4 qr4[16];
        #pragma unroll
        for (int r = 0; r < 16; ++r) qr4[r] = qp4[r];
        float4 acc4[4];
        #pragma unroll
        for (int r = 0; r < 4; ++r) acc4[r] = make_float4(0.f,0.f,0.f,0.f);
        float ssum = 0.f;
        int cend = (qt+1)*QB;

        for (int c0 = 0; c0 < cend; c0 += AC){
            {
                int half = tid >> 7;         // 0: K  1: V
                int idx2 = tid & 127;
                int r0 = idx2 >> 4;          // 0..7
                int d4 = idx2 & 15;
                #pragma unroll
                for (int rr = 0; rr < 4; ++rr){
                    int r = r0 + rr*8;
                    size_t tj = (size_t)(b*SEQ + c0 + r);
                    if (half == 0)
                        ((float4*)&k_sh[r][0])[d4] = *(const float4*)(kk + tj*INNER + hh*DHM + d4*4);
                    else
                        ((float4*)&v_sh[r][0])[d4] = *(const float4*)(up + tj*512 + hh*DHM + d4*4);
                }
            }
            __syncthreads();
            if (i >= c0){
                #pragma unroll
                for (int jj = 0; jj < 8; ++jj){
                    int jl = g*8 + jj;
                    const float4* kr = (const float4*)&k_sh[jl][0];
                    float d0=0.f, d1=0.f, d2=0.f, d3=0.f;
                    #pragma unroll
                    for (int r4 = 0; r4 < 4; ++r4){
                        float4 ka = kr[r4*4+0], kb2 = kr[r4*4+1];
                        float4 kc = kr[r4*4+2], kd  = kr[r4*4+3];
                        float4 qa = qr4[r4*4+0], qb2 = qr4[r4*4+1];
                        float4 qc = qr4[r4*4+2], qd  = qr4[r4*4+3];
                        d0 += qa.x*ka.x + qa.y*ka.y + qa.z*ka.z + qa.w*ka.w;
                        d1 += qb2.x*kb2.x + qb2.y*kb2.y + qb2.z*kb2.z + qb2.w*kb2.w;
                        d2 += qc.x*kc.x + qc.y*kc.y + qc.z*kc.z + qc.w*kc.w;
                        d3 += qd.x*kd.x + qd.y*kd.y + qd.z*kd.z + qd.w*kd.w;
                    }
                    float dot = (d0+d1) + (d2+d3);
                    int jg = c0 + jl;
                    float arg = fminf(csi + u_sh[jg] - m, 0.f);
                    S_sh[il][jl] = (jg <= i) ? dot * 0.125f * __expf(arg) : 0.f;
                }
            }
            __syncthreads();
            if (i >= c0){
                #pragma unroll
                for (int jj = 0; jj < AC; ++jj){
                    float sv = S_sh[il][jj];
                    ssum += sv;
                    const float4* vr = (const float4*)&v_sh[jj][g*16];
                    #pragma unroll
                    for (int r = 0; r < 4; ++r){
                        float4 vv = vr[r];
                        acc4[r].x += sv*vv.x; acc4[r].y += sv*vv.y;
                        acc4[r].z += sv*vv.z; acc4[r].w += sv*vv.w;
                    }
                }
            }
            __syncthreads();
        }
        float nrm = fmaxf(fabsf(ssum), __expf(-m)) + 1e-6f;
        float rn = 1.f/nrm;
        float4* op = (float4*)(q + ((size_t)(b*SEQ + i)*INNER + hh*DHM + g*16));
        #pragma unroll
        for (int r = 0; r < 4; ++r){
            float4 o = acc4[r];
            o.x *= rn; o.y *= rn; o.z *= rn; o.w *= rn;
            op[r] = o;
        }
    }
}

// ---------------- mh_gate: one WAVE per (t,h), coalesced -------------------------
__global__ void __launch_bounds__(256)
mh_gate_kernel(float* __restrict__ q, const float* __restrict__ up,
               const float* __restrict__ xc,
               const float* __restrict__ gnw, const float* __restrict__ skip)
{
    int unit = blockIdx.x*4 + (threadIdx.x >> 6);    // t*4 + hh
    int lane = threadIdx.x & 63;
    int t = unit >> 2, hh = unit & 3;
    int c = hh*DHM + lane;
    float v = q[(size_t)t*256 + c];
    float s = v, ss = v*v;
    #pragma unroll
    for (int off = 32; off >= 1; off >>= 1){ s += __shfl_xor(s,off); ss += __shfl_xor(ss,off); }
    float mu  = s * (1.f/64.f);
    float var = fmaxf(ss * (1.f/64.f) - mu*mu, 0.f);
    float r   = rsqrtf(var + 1e-6f);
    float hn  = (v-mu)*r*gnw[c];
    float z   = up[(size_t)t*512 + 256 + c];
    q[(size_t)t*256 + c] = (hn + skip[c]*xc[(size_t)t*256 + c]) * (z*sigf(z));
}

// ---------------- sLSTM gates: weight-stationary registers -----------------------
#define SG_TOK 16
__global__ void __launch_bounds__(512)
slstm_gates_kernel(const float* __restrict__ xc, const float* __restrict__ xl,
                   const float* __restrict__ Wg, const float* __restrict__ bg,
                   float* __restrict__ gates)
{
    int tid = threadIdx.x;
    int l  = tid & 31;
    int gn = tid >> 5;            // g*4+n
    int g  = gn >> 2, n = gn & 3;
    int t0 = blockIdx.x * SG_TOK;
    float wr[32];
    #pragma unroll
    for (int k = 0; k < 32; ++k) wr[k] = Wg[(size_t)gn*1024 + k*32 + l];
    float bias = bg[g*128 + n*32 + l];
    const float* xin = (g < 2) ? xc : xl;
    #pragma unroll 4
    for (int t = 0; t < SG_TOK; ++t){
        int tok = t0 + t;
        const float4* xr = (const float4*)(xin + (size_t)tok*128 + n*32);
        float a = bias;
        #pragma unroll
        for (int k4 = 0; k4 < 8; ++k4){
            float4 xv = xr[k4];
            a = fmaf(xv.x, wr[k4*4+0], a);
            a = fmaf(xv.y, wr[k4*4+1], a);
            a = fmaf(xv.z, wr[k4*4+2], a);
            a = fmaf(xv.w, wr[k4*4+3], a);
        }
        int b = tok >> 8, s = tok & 255;
        gates[(size_t)((b*4+n)*SEQ + s)*128 + l*4 + g] = a;
    }
}

// ---------------- sLSTM recurrence v4: chunked 8-deep gate prefetch --------------
// Round-10 counters: 925 cyc/step with only ~128 cyc VALU issue -> per-step gate
// load latency (gates=32MB, half HBM at ~900cyc) exposed by waitcnt each step.
// Fix: process 8 steps per chunk; issue all 8 float2 loads of chunk c+1 before
// computing chunk c (static indices -> registers). waitcnt lands once per 8
// steps -> latency amortized ~110 cyc/step. Math order identical.
__global__ void __launch_bounds__(64)
slstm_scan_kernel(const float* __restrict__ gates, const float* __restrict__ Rw,
                  float* __restrict__ ys)
{
    int bn = blockIdx.x;                 // b*4 + n
    int b = bn >> 2, n = bn & 3;
    int lane = threadIdx.x;              // 0..63
    int l = lane & 31;
    int hi = lane >> 5;                  // 0: gates i,f   1: gates z,o
    int gA = hi ? 2 : 0, gB = hi ? 3 : 1;
    const float* Rbase = Rw + (size_t)n*1024 + l;
    float Ra[32], Rb[32];
    #pragma unroll
    for (int k = 0; k < 32; ++k){
        Ra[k] = Rbase[(size_t)gA*4096 + k*32];
        Rb[k] = Rbase[(size_t)gB*4096 + k*32];
    }
    const float* gbase = gates + (size_t)bn*SEQ*128 + l*4 + (hi ? 2 : 0);
    float* yrow = ys + (size_t)b*SEQ*128 + n*32 + l;
    float2 cur[8], nxt[8];
    #pragma unroll
    for (int j = 0; j < 8; ++j) cur[j] = *(const float2*)(gbase + (size_t)j*128);
    float c = 0.f, nst = 0.f, m = 0.f, hst = 0.f;
    for (int ch = 0; ch < 32; ++ch){
        int nb = (ch < 31) ? (ch+1)*8 : 0;   // last chunk reloads 0 (unused)
        #pragma unroll
        for (int j = 0; j < 8; ++j)
            nxt[j] = *(const float2*)(gbase + (size_t)(nb + j)*128);
        #pragma unroll
        for (int j = 0; j < 8; ++j){
            float2 g0 = cur[j];
            float ra0=0.f, ra1=0.f, ra2=0.f, ra3=0.f;
            float rb0=0.f, rb1=0.f, rb2=0.f, rb3=0.f;
            #pragma unroll
            for (int k = 0; k < 8; ++k){
                float h0 = bcast_lane(hst, k);
                float h1 = bcast_lane(hst, k+8);
                float h2 = bcast_lane(hst, k+16);
                float h3 = bcast_lane(hst, k+24);
                ra0 = fmaf(h0, Ra[k],    ra0); rb0 = fmaf(h0, Rb[k],    rb0);
                ra1 = fmaf(h1, Ra[k+8],  ra1); rb1 = fmaf(h1, Rb[k+8],  rb1);
                ra2 = fmaf(h2, Ra[k+16], ra2); rb2 = fmaf(h2, Rb[k+16], rb2);
                ra3 = fmaf(h3, Ra[k+24], ra3); rb3 = fmaf(h3, Rb[k+24], rb3);
            }
            float ra = (ra0+ra1) + (ra2+ra3);
            float rb = (rb0+rb1) + (rb2+rb3);
            float pa = g0.x + ra;            // lo: ir   hi: zr
            float pb = g0.y + rb;            // lo: fr   hi: orr
            float zr  = __shfl_xor(pa, 32);
            float orr = __shfl_xor(pb, 32);
            float mnew = fmaxf(pb + m, pa);
            float iv = __expf(pa - mnew);
            float fv = __expf(pb + m - mnew);
            float zt = 1.f - 2.f*frcp(1.f + __expf(2.f*zr));
            float ov = frcp(1.f + __expf(-orr));
            c   = fv*c + iv*zt;
            nst = fv*nst + iv;
            hst = ov * c * frcp(nst + 1e-8f);
            m = mnew;
            if (!hi) yrow[(size_t)(ch*8 + j)*128] = hst;
        }
        #pragma unroll
        for (int j = 0; j < 8; ++j) cur[j] = nxt[j];
    }
}

// ---------------- mh_add: 32-lane group per (t,n), coalesced ---------------------
__global__ void __launch_bounds__(256)
mh_add_kernel(const float* __restrict__ ys, const float* __restrict__ gnw,
              float* __restrict__ h)
{
    int unit = blockIdx.x*8 + (threadIdx.x >> 5);    // t*4 + n
    int l = threadIdx.x & 31;
    int t = unit >> 2, n = unit & 3;
    float v = ys[(size_t)t*128 + n*32 + l];
    float s = v, ss = v*v;
    #pragma unroll
    for (int off = 16; off >= 1; off >>= 1){ s += __shfl_xor(s,off); ss += __shfl_xor(ss,off); }
    float mu  = s * (1.f/32.f);
    float var = fmaxf(ss * (1.f/32.f) - mu*mu, 0.f);
    float r   = rsqrtf(var + 1e-6f);
    h[(size_t)t*128 + n*32 + l] += (v-mu)*r*gnw[n*32+l];
}

__global__ void geluv_kernel(const float* __restrict__ up, float* __restrict__ out)
{
    int idx = blockIdx.x*blockDim.x + threadIdx.x;   // T*192
    if (idx >= T_TOK*FF) return;
    int j = idx % FF; int t = idx / FF;
    float g  = up[(size_t)t*384 + j];
    float vv = up[(size_t)t*384 + FF + j];
    float gel = 0.5f*g*(1.f + tanhf(0.7978845608028654f*(g + 0.044715f*g*g*g)));
    out[idx] = gel*vv;
}

// ---------------- final projection: fp32 output ----------------
__global__ void out_kernel(const float* __restrict__ ln, const float* __restrict__ W,
                           const float* __restrict__ bias, float* __restrict__ out)
{
    int idx = threadIdx.x;                           // 192 threads, 1 block
    if (idx >= BATCH*3) return;
    int b = idx / 3, e = idx % 3;
    float s = bias[e];
    const float* xr = ln + ((size_t)(b*SEQ + SEQ-1))*128;
    for (int d = 0; d < 128; ++d) s += xr[d]*W[d*3+e];
    out[idx] = s;
}

#define LCHK do { \
    if (hipGetLastError() != hipSuccess){ \
        sentinel_kernel<<<1, 192, 0, stream>>>((float*)d_out, 3000.0f + 32.0f*(float)launch_idx); \
        return; } \
    ++launch_idx; } while(0)

extern "C" void kernel_launch(void* const* d_in, const int* in_sizes, int n_in,
                              void* d_out, int out_size, void* d_ws, size_t ws_size,
                              hipStream_t stream)
{
    (void)out_size;
    static const int expected_sizes[30] = {
        49152, 384, 128, 512, 262144, 4096, 1024, 4096, 4096, 4096,
        12288, 16, 12288, 16, 1024, 1024, 131072, 256, 1024, 256,
        32768, 1024, 32768, 256, 256, 98304, 49152, 128, 384, 3
    };
    if (n_in != 30){ sentinel_kernel<<<1,192,0,stream>>>((float*)d_out, 5000.0f); return; }
    for (int i = 0; i < 30; ++i)
        if (in_sizes[i] != expected_sizes[i]){
            sentinel_kernel<<<1,192,0,stream>>>((float*)d_out, 2000.0f + 32.0f*i); return; }
    if (ws_size < (size_t)96*1024*1024){
        sentinel_kernel<<<1,192,0,stream>>>((float*)d_out, 1000.0f + (float)(ws_size >> 20)); return; }

    const float* x        = (const float*)d_in[0];
    const float* W_emb    = (const float*)d_in[1];
    const float* b_emb    = (const float*)d_in[2];
    const float* m_ln_w   = (const float*)d_in[3];
    const float* m_Wup    = (const float*)d_in[4];
    const float* m_conv_w = (const float*)d_in[5];
    const float* m_conv_b = (const float*)d_in[6];
    const float* m_Wq     = (const float*)d_in[7];
    const float* m_Wk     = (const float*)d_in[8];
    const float* m_Wv     = (const float*)d_in[9];
    const float* m_Wig    = (const float*)d_in[10];
    const float* m_big    = (const float*)d_in[11];
    const float* m_Wfg    = (const float*)d_in[12];
    const float* m_bfg    = (const float*)d_in[13];
    const float* m_gn_w   = (const float*)d_in[14];
    const float* m_skip   = (const float*)d_in[15];
    const float* m_Wdown  = (const float*)d_in[16];
    const float* s_ln_w   = (const float*)d_in[17];
    const float* s_conv_w = (const float*)d_in[18];
    const float* s_conv_b = (const float*)d_in[19];
    const float* s_Wg     = (const float*)d_in[20];
    const float* s_bg     = (const float*)d_in[21];
    const float* s_R      = (const float*)d_in[22];
    const float* s_gn_w   = (const float*)d_in[23];
    const float* s_ln2_w  = (const float*)d_in[24];
    const float* s_Wff_up = (const float*)d_in[25];
    const float* s_Wff_dn = (const float*)d_in[26];
    const float* post_ln  = (const float*)d_in[27];
    const float* W_out    = (const float*)d_in[28];
    const float* b_out    = (const float*)d_in[29];

    float* ws  = (float*)d_ws;
    float* h   = ws;                         // T*128
    float* ln  = h   + (size_t)T_TOK*128;    // T*128; igt/fgt/cs/pm alias (ln dead then)
    float* up  = ln  + (size_t)T_TOK*128;    // T*512
    float* xc  = up  + (size_t)T_TOK*512;    // T*256
    float* qb  = xc  + (size_t)T_TOK*256;    // T*256
    float* kb  = qb  + (size_t)T_TOK*256;    // T*256 (k; sLSTM ys)
    float* igt  = ln;
    float* fgt  = ln + 65536;
    float* csb  = ln + 2*65536;
    float* pmb  = ln + 3*65536;

    int launch_idx = 0;
    (void)hipGetLastError();

    embed_kernel<<<(T_TOK*128)/256, 256, 0, stream>>>(x, W_emb, b_emb, h); LCHK;

    const char* bt = "msmsmm";
    int mi = 0, si = 0;
    for (int blk = 0; blk < 6; ++blk){
        if (bt[blk] == 'm'){
            ln_kernel<<<T_TOK, 64, 0, stream>>>(h, m_ln_w + mi*128, ln); LCHK;
            gemm_tiled_m128_kernel<<<(T_TOK/HM)*(512/HN), 256, 0, stream>>>(ln, m_Wup + (size_t)mi*65536, up, T_TOK, 512, 128, 0); LCHK;
            conv_silu_kernel<<<(T_TOK*256)/256, 256, 0, stream>>>(up, 512, m_conv_w + mi*1024, m_conv_b + mi*256, xc, 256); LCHK;
            headwise_qk_kernel<<<(T_TOK*256)/256, 256, 0, stream>>>(xc, m_Wq + mi*1024, m_Wk + mi*1024, qb, kb); LCHK;
            headwise_inplace_kernel<<<(T_TOK*64)/256, 256, 0, stream>>>(up, m_Wv + mi*1024); LCHK;
            gateproj_kernel<<<T_TOK/4, 256, 0, stream>>>(qb, kb, up, m_Wig + mi*3072, m_big + mi*4,
                                                         m_Wfg + mi*3072, m_bfg + mi*4, igt, fgt); LCHK;
            cs_kernel<<<BATCH*NH, 64, 0, stream>>>(fgt, igt, csb, pmb); LCHK;
            attn_kernel<<<BATCH*NH*2, 256, 0, stream>>>(qb, kb, up, igt, csb, pmb); LCHK;
            mh_gate_kernel<<<T_TOK, 256, 0, stream>>>(qb, up, xc, m_gn_w + mi*256, m_skip + mi*256); LCHK;
            gemm_tiled_kernel<<<(T_TOK/TM)*(128/TN), 256, 0, stream>>>(qb, m_Wdown + (size_t)mi*32768, h, T_TOK, 128, 256, 1); LCHK;
            ++mi;
        } else {
            ln_kernel<<<T_TOK, 64, 0, stream>>>(h, s_ln_w + si*128, ln); LCHK;
            conv_silu_kernel<<<(T_TOK*128)/256, 256, 0, stream>>>(ln, 128, s_conv_w + si*512, s_conv_b + si*128, xc, 128); LCHK;
            slstm_gates_kernel<<<T_TOK/SG_TOK, 512, 0, stream>>>(xc, ln, s_Wg + si*16384, s_bg + si*512, up); LCHK;
            slstm_scan_kernel<<<BATCH*4, 64, 0, stream>>>(up, s_R + si*16384, kb); LCHK;
            mh_add_kernel<<<T_TOK/2, 256, 0, stream>>>(kb, s_gn_w + si*128, h); LCHK;
            ln_kernel<<<T_TOK, 64, 0, stream>>>(h, s_ln2_w + si*128, ln); LCHK;
            gemm_tiled_m128_kernel<<<(T_TOK/HM)*(384/HN), 256, 0, stream>>>(ln, s_Wff_up + (size_t)si*49152, up, T_TOK, 384, 128, 0); LCHK;
            geluv_kernel<<<(T_TOK*192)/256, 256, 0, stream>>>(up, qb); LCHK;
            gemm_tiled_kernel<<<(T_TOK/TM)*(128/TN), 256, 0, stream>>>(qb, s_Wff_dn + (size_t)si*24576, h, T_TOK, 128, 192, 1); LCHK;
            ++si;
        }
    }

    ln_kernel<<<T_TOK, 64, 0, stream>>>(h, post_ln, ln); LCHK;
    out_kernel<<<1, 192, 0, stream>>>(ln, W_out, b_out, (float*)d_out); LCHK;
}